// Round 1
// baseline (233.035 us; speedup 1.0000x reference)
//
#include <hip/hip_runtime.h>

#define DMODEL 768
#define NHEADS 12
#define MAXFULL 16

typedef __attribute__((ext_vector_type(8))) short short8;
typedef __attribute__((ext_vector_type(4))) float f32x4;

__device__ __forceinline__ unsigned pack2_bf16(float a, float b) {
  unsigned ua = __float_as_uint(a), ub = __float_as_uint(b);
  ua = (ua + 0x7fffu + ((ua >> 16) & 1u)) >> 16;
  ub = (ub + 0x7fffu + ((ub >> 16) & 1u)) & 0xffff0000u;
  return ua | ub;
}
__device__ __forceinline__ unsigned short bf16_1(float a) {
  unsigned ua = __float_as_uint(a);
  return (unsigned short)((ua + 0x7fffu + ((ua >> 16) & 1u)) >> 16);
}

// direct global->LDS DMA, 16 B per lane; LDS dest = wave-uniform base + lane*16
__device__ __forceinline__ void load16_lds(const void* g, void* l) {
  __builtin_amdgcn_global_load_lds(
      (const __attribute__((address_space(1))) unsigned int*)g,
      (__attribute__((address_space(3))) unsigned int*)l, 16, 0, 0);
}

// convert the 4 weight matrices f32 -> bf16 once
__global__ __launch_bounds__(256) void convW(const float* __restrict__ w0,
    const float* __restrict__ w1, const float* __restrict__ w2,
    const float* __restrict__ w3, unsigned* __restrict__ o0,
    unsigned* __restrict__ o1, unsigned* __restrict__ o2,
    unsigned* __restrict__ o3, int count) {
  const int nv = count >> 2;
  const float* src[4] = {w0, w1, w2, w3};
  unsigned* dst[4] = {o0, o1, o2, o3};
  for (int idx = blockIdx.x * 256 + threadIdx.x; idx < 4 * nv;
       idx += gridDim.x * 256) {
    int m = idx / nv, r = idx - m * nv;
    float4 v = ((const float4*)src[m])[r];
    dst[m][2 * r]     = pack2_bf16(v.x, v.y);
    dst[m][2 * r + 1] = pack2_bf16(v.z, v.w);
  }
}

// convert x_qk, x_v f32 -> bf16 once (removes pack VALU from the GEMM K-loop
// and halves A HBM bytes; enables global_load_lds staging — m97 recipe)
__global__ __launch_bounds__(256) void convX(const float* __restrict__ x0,
    const float* __restrict__ x1, unsigned* __restrict__ o0,
    unsigned* __restrict__ o1, int count) {
  const int nv = count >> 2;
  for (int idx = blockIdx.x * 256 + threadIdx.x; idx < 2 * nv;
       idx += gridDim.x * 256) {
    int m = idx / nv, r = idx - m * nv;
    float4 v = m ? ((const float4*)x1)[r] : ((const float4*)x0)[r];
    unsigned* d = m ? o1 : o0;
    d[2 * r]     = pack2_bf16(v.x, v.y);
    d[2 * r + 1] = pack2_bf16(v.z, v.w);
  }
}

struct GSeg {
  const unsigned short* A;   // bf16 activations [*,768]
  const unsigned short* W;   // bf16 weights [col][k]
  const float* bias;
  const int* row_map;        // optional row gather
  float* C;                  // f32 out
  int base;                  // first flat block id of this segment (mult of 8)
};

// m97-style GEMM, up to 3 fused segments: 128x128 tile, BK=32, 4 waves x
// (4x4 16x16x32 frags), global_load_lds width-16 staging into unpadded LDS
// (the __syncthreads vmcnt(0)+lgkmcnt(0) drain covers DMA completion), XCD
// swizzle for L2 locality. M per segment must be a multiple of 128 and
// (M/128) % 8 == 0 ... or == tile count covered by (xcd, j) exactly.
__global__ __launch_bounds__(256) void gemm128(GSeg g0, GSeg g1, GSeg g2) {
  __shared__ __attribute__((aligned(16))) unsigned short As[128 * 32];
  __shared__ __attribute__((aligned(16))) unsigned short Bs[128 * 32];
  const int t = threadIdx.x;
  const int id = blockIdx.x;
  const GSeg& d = (id >= g2.base) ? g2 : ((id >= g1.base) ? g1 : g0);
  const int lid = id - d.base;
  const int xcd = lid & 7, j = lid >> 3;
  const int bn = (j % 6) * 128;
  const int bm = ((j / 6) * 8 + xcd) * 128;
  const int lane = t & 63, wid = t >> 6;
  const int m16 = lane & 15, quad = lane >> 4;
  const int wm = (wid >> 1) * 64, wn = (wid & 1) * 64;

  f32x4 acc[4][4];
#pragma unroll
  for (int i = 0; i < 4; ++i)
#pragma unroll
    for (int j2 = 0; j2 < 4; ++j2) acc[i][j2] = (f32x4){0.f, 0.f, 0.f, 0.f};

  // staging: wave wid covers tile rows [wid*32, wid*32+32), 16 rows per issue,
  // lane covers row +lane/4, k-chunk (lane&3)*8 elems (16 B)
  const int srow = wid * 32 + (lane >> 2);
  const int skc = (lane & 3) * 8;
  int arow0, arow1;
  if (d.row_map) {
    arow0 = d.row_map[bm + srow];
    arow1 = d.row_map[bm + srow + 16];
  } else {
    arow0 = bm + srow;
    arow1 = bm + srow + 16;
  }
  const int wrow0 = bn + srow, wrow1 = bn + srow + 16;
  unsigned short* As0 = &As[(wid * 32) * 32];
  unsigned short* As1 = &As[(wid * 32 + 16) * 32];
  unsigned short* Bs0 = &Bs[(wid * 32) * 32];
  unsigned short* Bs1 = &Bs[(wid * 32 + 16) * 32];

  for (int k0 = 0; k0 < DMODEL; k0 += 32) {
    load16_lds(d.A + (size_t)arow0 * DMODEL + k0 + skc, As0);
    load16_lds(d.A + (size_t)arow1 * DMODEL + k0 + skc, As1);
    load16_lds(d.W + (size_t)wrow0 * DMODEL + k0 + skc, Bs0);
    load16_lds(d.W + (size_t)wrow1 * DMODEL + k0 + skc, Bs1);
    __syncthreads();   // drains vmcnt(0): DMA complete for all waves
    short8 a[4], b[4];
#pragma unroll
    for (int i = 0; i < 4; ++i)
      a[i] = *(const short8*)&As[(wm + i * 16 + m16) * 32 + quad * 8];
#pragma unroll
    for (int j2 = 0; j2 < 4; ++j2)
      b[j2] = *(const short8*)&Bs[(wn + j2 * 16 + m16) * 32 + quad * 8];
#pragma unroll
    for (int i = 0; i < 4; ++i)
#pragma unroll
      for (int j2 = 0; j2 < 4; ++j2)
        acc[i][j2] = __builtin_amdgcn_mfma_f32_16x16x32_bf16(a[i], b[j2], acc[i][j2], 0, 0, 0);
    __syncthreads();
  }

  // epilogue: C/D layout col=lane&15, row=quad*4+r (m89/m91)
  float bv[4]; int bcol[4];
#pragma unroll
  for (int j2 = 0; j2 < 4; ++j2) {
    bcol[j2] = bn + wn + j2 * 16 + m16;
    bv[j2] = d.bias[bcol[j2]];
  }
#pragma unroll
  for (int i = 0; i < 4; ++i) {
    const int rbase = bm + wm + i * 16 + quad * 4;
#pragma unroll
    for (int r = 0; r < 4; ++r) {
      const int row = rbase + r;
#pragma unroll
      for (int j2 = 0; j2 < 4; ++j2)
        d.C[(size_t)row * DMODEL + bcol[j2]] = acc[i][j2][r] + bv[j2];
    }
  }
}

// one block: prefix-scan query_mask -> left/right/nvalid per feature,
// plus compact list of fully-masked features (nvalid==0).
__global__ __launch_bounds__(1024) void build_segments(const int* __restrict__ qm,
    const int* __restrict__ ids, const int* __restrict__ padp,
    int n, int f, int* __restrict__ left, int* __restrict__ right,
    int* __restrict__ nvalid, int* __restrict__ fullrank,
    int* __restrict__ fullist, int* __restrict__ nfull) {
  __shared__ int cnt[1024];
  __shared__ int fullcnt;
  const int t = threadIdx.x;
  if (t == 0) fullcnt = 0;
  const int per = (n + 1023) >> 10;
  const int base = t * per;
  int c = 0;
  for (int i = 0; i < per; ++i) {
    int p = base + i;
    if (p < n && qm[p] != 0) ++c;
  }
  cnt[t] = c;
  __syncthreads();
  for (int off = 1; off < 1024; off <<= 1) {
    int v = (t >= off) ? cnt[t - off] : 0;
    __syncthreads();
    cnt[t] += v;
    __syncthreads();
  }
  int r = cnt[t] - c;  // exclusive prefix
  for (int i = 0; i < per; ++i) {
    int p = base + i;
    if (p < n && qm[p] != 0) {
      if (r < f) left[r] = p;
      ++r;
    }
  }
  __syncthreads();
  const int pad = *padp;
  for (int i = t; i < f; i += 1024) {
    int L0 = left[i];
    int R0 = (i + 1 < f) ? left[i + 1] : n;
    right[i] = R0;
    int cv = 0;
    for (int p = L0; p < R0; ++p) cv += (ids[p] != pad) ? 1 : 0;
    nvalid[i] = cv;
    if (cv == 0) {
      int rk = atomicAdd(&fullcnt, 1);
      if (rk < MAXFULL) { fullist[rk] = i; fullrank[i] = rk; }
      else fullrank[i] = -1;
    } else {
      fullrank[i] = -1;
    }
  }
  __syncthreads();
  if (t == 0) *nfull = (fullcnt < MAXFULL) ? fullcnt : MAXFULL;
}

__device__ __forceinline__ float allreduce64(float x) {
#pragma unroll
  for (int m = 1; m < 64; m <<= 1) x += __shfl_xor(x, m, 64);
  return x;
}

// normal features: online softmax over the (short) segment, skipping pad keys.
// Out-of-segment/pad contributions underflow to exact 0 in the reference's f32
// softmax, so segment-only is exact. Writes bf16 (input to the Wo GEMM).
__global__ __launch_bounds__(64) void attn_seg(const float* __restrict__ q,
    const float* __restrict__ k, const float* __restrict__ v,
    const int* __restrict__ left, const int* __restrict__ right,
    const int* __restrict__ nvalid, const int* __restrict__ ids,
    const int* __restrict__ padp, unsigned short* __restrict__ out) {
  const int feat = blockIdx.x, h = blockIdx.y, lane = threadIdx.x;
  if (nvalid[feat] == 0) return;  // handled by attn_full_*
  const int off = h * 64 + lane;
  const int pad = *padp;
  const float qv = q[(size_t)feat * DMODEL + off];
  float m = -1e30f, l = 0.f, acc = 0.f;
  const int L0 = left[feat], R0 = right[feat];
  for (int p = L0; p < R0; ++p) {
    if (ids[p] == pad) continue;
    float s = allreduce64(qv * k[(size_t)p * DMODEL + off]) * 0.125f;
    float mn = fmaxf(m, s);
    float al = __expf(m - mn);
    float w = __expf(s - mn);
    l = l * al + w;
    acc = acc * al + w * v[(size_t)p * DMODEL + off];
    m = mn;
  }
  out[(size_t)feat * DMODEL + off] = bf16_1(acc / l);
}

// fully-masked features: uniform -10000 bias cancels in softmax -> full softmax
// over ALL n keys (pads included, cross-batch).
__global__ __launch_bounds__(256) void attn_full_part(const float* __restrict__ q,
    const float* __restrict__ k, const float* __restrict__ v,
    const int* __restrict__ fullist, const int* __restrict__ nfullp,
    int n, int P, float* __restrict__ pm, float* __restrict__ pl,
    float* __restrict__ pacc) {
  const int nfull = *nfullp;
  if (nfull == 0) return;
  const int t = threadIdx.x, lane = t & 63, wv = t >> 6;
  const int gw = blockIdx.x * 4 + wv;     // P % 4 == 0 -> block-uniform head
  const int h = gw / P, piece = gw - h * P;
  const int pk = n / P;                    // keys per piece (multiple of 64)

  __shared__ float q_lds[8 * 64];
  __shared__ float w_lds[4][64 * 8];       // [wave][key][feat], 32B-aligned rows

  for (int idx = t; idx < 8 * 64; idx += 256) {
    int fl = idx >> 6, d = idx & 63;
    q_lds[idx] = (fl < nfull) ? q[(size_t)fullist[fl] * DMODEL + h * 64 + d] : 0.f;
  }
  __syncthreads();

  float m[8], l[8], acc[8];
#pragma unroll
  for (int f_ = 0; f_ < 8; ++f_) { m[f_] = -1e30f; l[f_] = 0.f; acc[f_] = 0.f; }

  for (int c = 0; c < pk; c += 64) {
    const int pc = piece * pk + c;
    float s[8];
#pragma unroll
    for (int f_ = 0; f_ < 8; ++f_) s[f_] = 0.f;
    const float4* kp = (const float4*)(k + (size_t)(pc + lane) * DMODEL + h * 64);
#pragma unroll 1
    for (int g = 0; g < 2; ++g) {
      float4 kv0 = kp[g * 8 + 0], kv1 = kp[g * 8 + 1], kv2 = kp[g * 8 + 2],
             kv3 = kp[g * 8 + 3], kv4 = kp[g * 8 + 4], kv5 = kp[g * 8 + 5],
             kv6 = kp[g * 8 + 6], kv7 = kp[g * 8 + 7];
      const float4* qb = (const float4*)&q_lds[g * 32];
#pragma unroll
      for (int f_ = 0; f_ < 8; ++f_) {
        float4 q0 = qb[f_ * 16 + 0], q1 = qb[f_ * 16 + 1], q2 = qb[f_ * 16 + 2],
               q3 = qb[f_ * 16 + 3], q4 = qb[f_ * 16 + 4], q5 = qb[f_ * 16 + 5],
               q6 = qb[f_ * 16 + 6], q7 = qb[f_ * 16 + 7];
        float acc0 = q0.x * kv0.x + q0.y * kv0.y + q0.z * kv0.z + q0.w * kv0.w;
        acc0 += q1.x * kv1.x + q1.y * kv1.y + q1.z * kv1.z + q1.w * kv1.w;
        acc0 += q2.x * kv2.x + q2.y * kv2.y + q2.z * kv2.z + q2.w * kv2.w;
        acc0 += q3.x * kv3.x + q3.y * kv3.y + q3.z * kv3.z + q3.w * kv3.w;
        acc0 += q4.x * kv4.x + q4.y * kv4.y + q4.z * kv4.z + q4.w * kv4.w;
        acc0 += q5.x * kv5.x + q5.y * kv5.y + q5.z * kv5.z + q5.w * kv5.w;
        acc0 += q6.x * kv6.x + q6.y * kv6.y + q6.z * kv6.z + q6.w * kv6.w;
        acc0 += q7.x * kv7.x + q7.y * kv7.y + q7.z * kv7.z + q7.w * kv7.w;
        s[f_] += acc0;
      }
    }
    float mx[8];
#pragma unroll
    for (int f_ = 0; f_ < 8; ++f_) mx[f_] = s[f_] * 0.125f;
#pragma unroll
    for (int f_ = 0; f_ < 8; ++f_) s[f_] = mx[f_];
#pragma unroll
    for (int st = 1; st < 64; st <<= 1)
#pragma unroll
      for (int f_ = 0; f_ < 8; ++f_) mx[f_] = fmaxf(mx[f_], __shfl_xor(mx[f_], st, 64));
    float alpha[8], w[8], sum[8];
#pragma unroll
    for (int f_ = 0; f_ < 8; ++f_) {
      float mn = fmaxf(m[f_], mx[f_]);
      alpha[f_] = __expf(m[f_] - mn);
      w[f_] = __expf(s[f_] - mn);
      m[f_] = mn;
      sum[f_] = w[f_];
    }
#pragma unroll
    for (int st = 1; st < 64; st <<= 1)
#pragma unroll
      for (int f_ = 0; f_ < 8; ++f_) sum[f_] += __shfl_xor(sum[f_], st, 64);
#pragma unroll
    for (int f_ = 0; f_ < 8; ++f_) l[f_] = l[f_] * alpha[f_] + sum[f_];
    *(float4*)&w_lds[wv][lane * 8]     = make_float4(w[0], w[1], w[2], w[3]);
    *(float4*)&w_lds[wv][lane * 8 + 4] = make_float4(w[4], w[5], w[6], w[7]);
#pragma unroll
    for (int f_ = 0; f_ < 8; ++f_) acc[f_] *= alpha[f_];
    const float* vb = v + (size_t)pc * DMODEL + h * 64 + lane;
#pragma unroll 4
    for (int kk = 0; kk < 64; ++kk) {
      float vd = vb[(size_t)kk * DMODEL];
      float4 wa = *(const float4*)&w_lds[wv][kk * 8];
      float4 wb = *(const float4*)&w_lds[wv][kk * 8 + 4];
      acc[0] += wa.x * vd; acc[1] += wa.y * vd; acc[2] += wa.z * vd; acc[3] += wa.w * vd;
      acc[4] += wb.x * vd; acc[5] += wb.y * vd; acc[6] += wb.z * vd; acc[7] += wb.w * vd;
    }
  }

  for (int f_ = 0; f_ < nfull; ++f_) {
    size_t idx = ((size_t)f_ * NHEADS + h) * P + piece;
    if (lane == 0) { pm[idx] = m[f_]; pl[idx] = l[f_]; }
    pacc[idx * 64 + lane] = acc[f_];
  }
}

// Split-K pass 2: merge the P partials per (full-feature, head). Writes bf16.
__global__ __launch_bounds__(256) void attn_full_comb(
    const int* __restrict__ fullist, const int* __restrict__ nfullp,
    int P, const float* __restrict__ pm, const float* __restrict__ pl,
    const float* __restrict__ pacc, unsigned short* __restrict__ out) {
  const int fl = blockIdx.x, h = blockIdx.y;
  if (fl >= *nfullp) return;
  const int feat = fullist[fl];
  const int t = threadIdx.x, lane = t & 63, wv = t >> 6;
  const size_t base = ((size_t)fl * NHEADS + h) * P;

  __shared__ float s_pm[128];    // P <= 128
  __shared__ float s_sc[128];
  __shared__ float s_red[4];
  __shared__ float s_part[4][64];

  for (int sp = t; sp < P; sp += 256) s_pm[sp] = pm[base + sp];
  __syncthreads();
  float mloc = -1e30f;
  for (int sp = t; sp < P; sp += 256) mloc = fmaxf(mloc, s_pm[sp]);
#pragma unroll
  for (int st = 1; st < 64; st <<= 1) mloc = fmaxf(mloc, __shfl_xor(mloc, st, 64));
  if (lane == 0) s_red[wv] = mloc;
  __syncthreads();
  const float M = fmaxf(fmaxf(s_red[0], s_red[1]), fmaxf(s_red[2], s_red[3]));
  __syncthreads();
  float lloc = 0.f;
  for (int sp = t; sp < P; sp += 256) {
    float sc = __expf(s_pm[sp] - M);
    s_sc[sp] = sc;
    lloc += pl[base + sp] * sc;
  }
#pragma unroll
  for (int st = 1; st < 64; st <<= 1) lloc += __shfl_xor(lloc, st, 64);
  if (lane == 0) s_red[wv] = lloc;
  __syncthreads();
  const float Lt = s_red[0] + s_red[1] + s_red[2] + s_red[3];
  float At = 0.f;
  for (int sp = wv; sp < P; sp += 4)
    At += pacc[(base + sp) * 64 + lane] * s_sc[sp];
  s_part[wv][lane] = At;
  __syncthreads();
  if (wv == 0) {
    float tot = s_part[0][lane] + s_part[1][lane] + s_part[2][lane] + s_part[3][lane];
    out[(size_t)feat * DMODEL + h * 64 + lane] = bf16_1(tot / Lt);
  }
}

extern "C" void kernel_launch(void* const* d_in, const int* in_sizes, int n_in,
                              void* d_out, int out_size, void* d_ws, size_t ws_size,
                              hipStream_t stream) {
  const float* x_qk = (const float*)d_in[0];
  const float* x_v  = (const float*)d_in[1];
  const int* qm     = (const int*)d_in[2];
  const int* ids    = (const int*)d_in[3];
  const int* padp   = (const int*)d_in[4];
  const float* Wq = (const float*)d_in[5];
  const float* bq = (const float*)d_in[6];
  const float* Wk = (const float*)d_in[7];
  const float* bk = (const float*)d_in[8];
  const float* Wv = (const float*)d_in[9];
  const float* bv = (const float*)d_in[10];
  const float* Wo = (const float*)d_in[11];
  const float* bo = (const float*)d_in[12];

  const int n = in_sizes[0] / DMODEL;   // 8192
  const int f = out_size / DMODEL;      // 1024

  // ws: kf,vf,qf f32 | af bf16 | Wbf x4 | xqb,xvb bf16 | ints | split partials
  float* kf = (float*)d_ws;
  float* vf = kf + (size_t)n * DMODEL;
  float* qf = vf + (size_t)n * DMODEL;
  unsigned short* af = (unsigned short*)(qf + (size_t)f * DMODEL);
  unsigned short* wqb = af + (size_t)f * DMODEL;
  unsigned short* wkb = wqb + DMODEL * DMODEL;
  unsigned short* wvb = wkb + DMODEL * DMODEL;
  unsigned short* wob = wvb + DMODEL * DMODEL;
  unsigned short* xqb = wob + DMODEL * DMODEL;
  unsigned short* xvb = xqb + (size_t)n * DMODEL;
  int* left     = (int*)(xvb + (size_t)n * DMODEL);
  int* right    = left + f;
  int* nvalid   = right + f;
  int* fullrank = nvalid + f;
  int* fullist  = fullrank + f;
  int* nfull    = fullist + MAXFULL;
  size_t off_bytes = ((size_t)((char*)(nfull + 1) - (char*)d_ws) + 255) & ~(size_t)255;
  int P = 128;
  while (P > 16) {
    size_t need = (size_t)MAXFULL * NHEADS * P * 66 * sizeof(float);
    if (off_bytes + need <= ws_size && (n / P) % 64 == 0 && n % P == 0) break;
    P >>= 1;
  }
  float* pm = (float*)((char*)d_ws + off_bytes);
  float* pl = pm + (size_t)MAXFULL * NHEADS * P;
  float* pacc = pl + (size_t)MAXFULL * NHEADS * P;

  build_segments<<<1, 1024, 0, stream>>>(qm, ids, padp, n, f, left, right,
                                         nvalid, fullrank, fullist, nfull);
  convW<<<1152, 256, 0, stream>>>(Wq, Wk, Wv, Wo, (unsigned*)wqb, (unsigned*)wkb,
                                  (unsigned*)wvb, (unsigned*)wob, DMODEL * DMODEL);
  convX<<<2048, 256, 0, stream>>>(x_qk, x_v, (unsigned*)xqb, (unsigned*)xvb,
                                  n * DMODEL);

  const int TKV = 6 * (n / 128);   // 384 blocks/segment, (n/128)%8==0
  const int TF  = 6 * (f / 128);   // 48 blocks, f/128 == 8
  GSeg g0 = { xqb, wkb, bk, nullptr, kf, 0 };
  GSeg g1 = { xvb, wvb, bv, nullptr, vf, TKV };
  GSeg g2 = { xqb, wqb, bq, left,    qf, 2 * TKV };
  gemm128<<<2 * TKV + TF, 256, 0, stream>>>(g0, g1, g2);

  attn_seg<<<dim3(f, NHEADS), 64, 0, stream>>>(qf, kf, vf, left, right, nvalid,
                                               ids, padp, af);
  attn_full_part<<<NHEADS * P / 4, 256, 0, stream>>>(qf, kf, vf, fullist, nfull,
                                                     n, P, pm, pl, pacc);
  attn_full_comb<<<dim3(MAXFULL, NHEADS), 256, 0, stream>>>(fullist, nfull, P,
                                                            pm, pl, pacc, af);

  GSeg gout = { af, wob, bo, nullptr, (float*)d_out, 0 };
  GSeg gnull = { af, wob, bo, nullptr, (float*)d_out, 1 << 30 };
  gemm128<<<TF, 256, 0, stream>>>(gout, gnull, gnull);
}

// Round 2
// 232.298 us; speedup vs baseline: 1.0032x; 1.0032x over previous
//
#include <hip/hip_runtime.h>

#define DMODEL 768
#define NHEADS 12
#define MAXFULL 16
#define NSTEP 24   // DMODEL / 32

typedef __attribute__((ext_vector_type(8))) short short8;
typedef __attribute__((ext_vector_type(4))) float f32x4;

__device__ __forceinline__ unsigned pack2_bf16(float a, float b) {
  unsigned ua = __float_as_uint(a), ub = __float_as_uint(b);
  ua = (ua + 0x7fffu + ((ua >> 16) & 1u)) >> 16;
  ub = (ub + 0x7fffu + ((ub >> 16) & 1u)) & 0xffff0000u;
  return ua | ub;
}
__device__ __forceinline__ unsigned short bf16_1(float a) {
  unsigned ua = __float_as_uint(a);
  return (unsigned short)((ua + 0x7fffu + ((ua >> 16) & 1u)) >> 16);
}

// direct global->LDS DMA, 16 B per lane; LDS dest = wave-uniform base + lane*16
__device__ __forceinline__ void load16_lds(const void* g, void* l) {
  __builtin_amdgcn_global_load_lds(
      (const __attribute__((address_space(1))) unsigned int*)g,
      (__attribute__((address_space(3))) unsigned int*)l, 16, 0, 0);
}

// convert the 4 weight matrices f32 -> bf16 once
__global__ __launch_bounds__(256) void convW(const float* __restrict__ w0,
    const float* __restrict__ w1, const float* __restrict__ w2,
    const float* __restrict__ w3, unsigned* __restrict__ o0,
    unsigned* __restrict__ o1, unsigned* __restrict__ o2,
    unsigned* __restrict__ o3, int count) {
  const int nv = count >> 2;
  const float* src[4] = {w0, w1, w2, w3};
  unsigned* dst[4] = {o0, o1, o2, o3};
  for (int idx = blockIdx.x * 256 + threadIdx.x; idx < 4 * nv;
       idx += gridDim.x * 256) {
    int m = idx / nv, r = idx - m * nv;
    float4 v = ((const float4*)src[m])[r];
    dst[m][2 * r]     = pack2_bf16(v.x, v.y);
    dst[m][2 * r + 1] = pack2_bf16(v.z, v.w);
  }
}

// convert x_qk, x_v f32 -> bf16 once
__global__ __launch_bounds__(256) void convX(const float* __restrict__ x0,
    const float* __restrict__ x1, unsigned* __restrict__ o0,
    unsigned* __restrict__ o1, int count) {
  const int nv = count >> 2;
  for (int idx = blockIdx.x * 256 + threadIdx.x; idx < 2 * nv;
       idx += gridDim.x * 256) {
    int m = idx / nv, r = idx - m * nv;
    float4 v = m ? ((const float4*)x1)[r] : ((const float4*)x0)[r];
    unsigned* d = m ? o1 : o0;
    d[2 * r]     = pack2_bf16(v.x, v.y);
    d[2 * r + 1] = pack2_bf16(v.z, v.w);
  }
}

struct GSeg {
  const unsigned short* A;   // bf16 activations [*,768]
  const unsigned short* W;   // bf16 weights [col][k]
  const float* bias;
  const int* row_map;        // optional row gather
  float* C;                  // f32 out
  int base;                  // first flat block id of this segment (mult of 8)
};

__device__ __forceinline__ void stage_step(const GSeg& d, int k0, int arow0,
    int arow1, int wrow0, int wrow1, int skc, unsigned short* AsB,
    unsigned short* BsB, int woff) {
  load16_lds(d.A + (size_t)arow0 * DMODEL + k0 + skc, AsB + woff);
  load16_lds(d.A + (size_t)arow1 * DMODEL + k0 + skc, AsB + woff + 16 * 32);
  load16_lds(d.W + (size_t)wrow0 * DMODEL + k0 + skc, BsB + woff);
  load16_lds(d.W + (size_t)wrow1 * DMODEL + k0 + skc, BsB + woff + 16 * 32);
}

__device__ __forceinline__ void compute_step(const unsigned short* AsB,
    const unsigned short* BsB, int wm, int wn, int m16, int quad,
    f32x4 acc[4][4]) {
  short8 a[4], b[4];
#pragma unroll
  for (int i = 0; i < 4; ++i)
    a[i] = *(const short8*)&AsB[(wm + i * 16 + m16) * 32 + quad * 8];
#pragma unroll
  for (int j2 = 0; j2 < 4; ++j2)
    b[j2] = *(const short8*)&BsB[(wn + j2 * 16 + m16) * 32 + quad * 8];
#pragma unroll
  for (int i = 0; i < 4; ++i)
#pragma unroll
    for (int j2 = 0; j2 < 4; ++j2)
      acc[i][j2] = __builtin_amdgcn_mfma_f32_16x16x32_bf16(a[i], b[j2], acc[i][j2], 0, 0, 0);
}

// pipelined m97-style GEMM, up to 3 fused segments: 128x128 tile, BK=32,
// 3-deep LDS ring + counted vmcnt (T3/T4): loads for steps t+1..t+3 stay in
// flight across barriers instead of a full vmcnt(0) drain per step.
__global__ __launch_bounds__(256) void gemm128(GSeg g0, GSeg g1, GSeg g2) {
  __shared__ __attribute__((aligned(16))) unsigned short As[3][128 * 32];
  __shared__ __attribute__((aligned(16))) unsigned short Bs[3][128 * 32];
  const int t = threadIdx.x;
  const int id = blockIdx.x;
  const GSeg& d = (id >= g2.base) ? g2 : ((id >= g1.base) ? g1 : g0);
  const int lid = id - d.base;
  const int xcd = lid & 7, j = lid >> 3;
  const int bn = (j % 6) * 128;
  const int bm = ((j / 6) * 8 + xcd) * 128;
  const int lane = t & 63, wid = t >> 6;
  const int m16 = lane & 15, quad = lane >> 4;
  const int wm = (wid >> 1) * 64, wn = (wid & 1) * 64;

  f32x4 acc[4][4];
#pragma unroll
  for (int i = 0; i < 4; ++i)
#pragma unroll
    for (int j2 = 0; j2 < 4; ++j2) acc[i][j2] = (f32x4){0.f, 0.f, 0.f, 0.f};

  // staging: wave wid covers tile rows [wid*32, wid*32+32), 16 rows per issue,
  // lane covers row +lane/4, k-chunk (lane&3)*8 elems (16 B)
  const int srow = wid * 32 + (lane >> 2);
  const int skc = (lane & 3) * 8;
  int arow0, arow1;
  if (d.row_map) {
    arow0 = d.row_map[bm + srow];
    arow1 = d.row_map[bm + srow + 16];
  } else {
    arow0 = bm + srow;
    arow1 = bm + srow + 16;
  }
  const int wrow0 = bn + srow, wrow1 = bn + srow + 16;
  const int woff = (wid * 32) * 32;

  // prologue: stage steps 0,1,2 into ring buffers 0,1,2 (12 loads/wave)
  stage_step(d, 0,  arow0, arow1, wrow0, wrow1, skc, &As[0][0], &Bs[0][0], woff);
  stage_step(d, 32, arow0, arow1, wrow0, wrow1, skc, &As[1][0], &Bs[1][0], woff);
  stage_step(d, 64, arow0, arow1, wrow0, wrow1, skc, &As[2][0], &Bs[2][0], woff);

#pragma unroll 1
  for (int g = 0; g < (NSTEP - 3) / 3; ++g) {   // steps 0..20, groups of 3
    const int t0 = g * 3;
#pragma unroll
    for (int u = 0; u < 3; ++u) {
      const int ts = t0 + u;
      asm volatile("s_waitcnt vmcnt(8)" ::: "memory");  // step ts's 4 loads done
      __builtin_amdgcn_s_barrier();                     // ... for ALL waves
      __builtin_amdgcn_sched_barrier(0);
      compute_step(&As[u][0], &Bs[u][0], wm, wn, m16, quad, acc);
      __builtin_amdgcn_s_barrier();                     // all waves done reading
      __builtin_amdgcn_sched_barrier(0);
      stage_step(d, (ts + 3) * 32, arow0, arow1, wrow0, wrow1, skc,
                 &As[u][0], &Bs[u][0], woff);
    }
  }
  // epilogue: steps 21,22,23 in buffers 0,1,2; drain 8 -> 4 -> 0
  asm volatile("s_waitcnt vmcnt(8)" ::: "memory");
  __builtin_amdgcn_s_barrier();
  __builtin_amdgcn_sched_barrier(0);
  compute_step(&As[0][0], &Bs[0][0], wm, wn, m16, quad, acc);
  asm volatile("s_waitcnt vmcnt(4)" ::: "memory");
  __builtin_amdgcn_s_barrier();
  __builtin_amdgcn_sched_barrier(0);
  compute_step(&As[1][0], &Bs[1][0], wm, wn, m16, quad, acc);
  asm volatile("s_waitcnt vmcnt(0)" ::: "memory");
  __builtin_amdgcn_s_barrier();
  __builtin_amdgcn_sched_barrier(0);
  compute_step(&As[2][0], &Bs[2][0], wm, wn, m16, quad, acc);

  // epilogue: C/D layout col=lane&15, row=quad*4+r (m89/m91)
  float bv[4]; int bcol[4];
#pragma unroll
  for (int j2 = 0; j2 < 4; ++j2) {
    bcol[j2] = bn + wn + j2 * 16 + m16;
    bv[j2] = d.bias[bcol[j2]];
  }
#pragma unroll
  for (int i = 0; i < 4; ++i) {
    const int rbase = bm + wm + i * 16 + quad * 4;
#pragma unroll
    for (int r = 0; r < 4; ++r) {
      const int row = rbase + r;
#pragma unroll
      for (int j2 = 0; j2 < 4; ++j2)
        d.C[(size_t)row * DMODEL + bcol[j2]] = acc[i][j2][r] + bv[j2];
    }
  }
}

// one block: prefix-scan query_mask -> left/right/nvalid per feature,
// plus compact list of fully-masked features (nvalid==0).
__global__ __launch_bounds__(1024) void build_segments(const int* __restrict__ qm,
    const int* __restrict__ ids, const int* __restrict__ padp,
    int n, int f, int* __restrict__ left, int* __restrict__ right,
    int* __restrict__ nvalid, int* __restrict__ fullrank,
    int* __restrict__ fullist, int* __restrict__ nfull) {
  __shared__ int cnt[1024];
  __shared__ int fullcnt;
  const int t = threadIdx.x;
  if (t == 0) fullcnt = 0;
  const int per = (n + 1023) >> 10;
  const int base = t * per;
  int c = 0;
  for (int i = 0; i < per; ++i) {
    int p = base + i;
    if (p < n && qm[p] != 0) ++c;
  }
  cnt[t] = c;
  __syncthreads();
  for (int off = 1; off < 1024; off <<= 1) {
    int v = (t >= off) ? cnt[t - off] : 0;
    __syncthreads();
    cnt[t] += v;
    __syncthreads();
  }
  int r = cnt[t] - c;  // exclusive prefix
  for (int i = 0; i < per; ++i) {
    int p = base + i;
    if (p < n && qm[p] != 0) {
      if (r < f) left[r] = p;
      ++r;
    }
  }
  __syncthreads();
  const int pad = *padp;
  for (int i = t; i < f; i += 1024) {
    int L0 = left[i];
    int R0 = (i + 1 < f) ? left[i + 1] : n;
    right[i] = R0;
    int cv = 0;
    for (int p = L0; p < R0; ++p) cv += (ids[p] != pad) ? 1 : 0;
    nvalid[i] = cv;
    if (cv == 0) {
      int rk = atomicAdd(&fullcnt, 1);
      if (rk < MAXFULL) { fullist[rk] = i; fullrank[i] = rk; }
      else fullrank[i] = -1;
    } else {
      fullrank[i] = -1;
    }
  }
  __syncthreads();
  if (t == 0) *nfull = (fullcnt < MAXFULL) ? fullcnt : MAXFULL;
}

__device__ __forceinline__ float allreduce64(float x) {
#pragma unroll
  for (int m = 1; m < 64; m <<= 1) x += __shfl_xor(x, m, 64);
  return x;
}

// normal features: online softmax over the (short) segment, skipping pad keys.
// 4 features per 256-thread block (one wave each) for occupancy; no barriers,
// per-wave early-exit is safe.
__global__ __launch_bounds__(256) void attn_seg(const float* __restrict__ q,
    const float* __restrict__ k, const float* __restrict__ v,
    const int* __restrict__ left, const int* __restrict__ right,
    const int* __restrict__ nvalid, const int* __restrict__ ids,
    const int* __restrict__ padp, unsigned short* __restrict__ out) {
  const int wid = threadIdx.x >> 6, lane = threadIdx.x & 63;
  const int feat = blockIdx.x * 4 + wid, h = blockIdx.y;
  if (nvalid[feat] == 0) return;  // handled by attn_full_*
  const int off = h * 64 + lane;
  const int pad = *padp;
  const float qv = q[(size_t)feat * DMODEL + off];
  float m = -1e30f, l = 0.f, acc = 0.f;
  const int L0 = left[feat], R0 = right[feat];
  for (int p = L0; p < R0; ++p) {
    if (ids[p] == pad) continue;
    float s = allreduce64(qv * k[(size_t)p * DMODEL + off]) * 0.125f;
    float mn = fmaxf(m, s);
    float al = __expf(m - mn);
    float w = __expf(s - mn);
    l = l * al + w;
    acc = acc * al + w * v[(size_t)p * DMODEL + off];
    m = mn;
  }
  out[(size_t)feat * DMODEL + off] = bf16_1(acc / l);
}

// fully-masked features: uniform -10000 bias cancels in softmax -> full softmax
// over ALL n keys (pads included, cross-batch).
__global__ __launch_bounds__(256) void attn_full_part(const float* __restrict__ q,
    const float* __restrict__ k, const float* __restrict__ v,
    const int* __restrict__ fullist, const int* __restrict__ nfullp,
    int n, int P, float* __restrict__ pm, float* __restrict__ pl,
    float* __restrict__ pacc) {
  const int nfull = *nfullp;
  if (nfull == 0) return;
  const int t = threadIdx.x, lane = t & 63, wv = t >> 6;
  const int gw = blockIdx.x * 4 + wv;     // P % 4 == 0 -> block-uniform head
  const int h = gw / P, piece = gw - h * P;
  const int pk = n / P;                    // keys per piece (multiple of 64)

  __shared__ float q_lds[8 * 64];
  __shared__ float w_lds[4][64 * 8];       // [wave][key][feat], 32B-aligned rows

  for (int idx = t; idx < 8 * 64; idx += 256) {
    int fl = idx >> 6, d = idx & 63;
    q_lds[idx] = (fl < nfull) ? q[(size_t)fullist[fl] * DMODEL + h * 64 + d] : 0.f;
  }
  __syncthreads();

  float m[8], l[8], acc[8];
#pragma unroll
  for (int f_ = 0; f_ < 8; ++f_) { m[f_] = -1e30f; l[f_] = 0.f; acc[f_] = 0.f; }

  for (int c = 0; c < pk; c += 64) {
    const int pc = piece * pk + c;
    float s[8];
#pragma unroll
    for (int f_ = 0; f_ < 8; ++f_) s[f_] = 0.f;
    const float4* kp = (const float4*)(k + (size_t)(pc + lane) * DMODEL + h * 64);
#pragma unroll 1
    for (int g = 0; g < 2; ++g) {
      float4 kv0 = kp[g * 8 + 0], kv1 = kp[g * 8 + 1], kv2 = kp[g * 8 + 2],
             kv3 = kp[g * 8 + 3], kv4 = kp[g * 8 + 4], kv5 = kp[g * 8 + 5],
             kv6 = kp[g * 8 + 6], kv7 = kp[g * 8 + 7];
      const float4* qb = (const float4*)&q_lds[g * 32];
#pragma unroll
      for (int f_ = 0; f_ < 8; ++f_) {
        float4 q0 = qb[f_ * 16 + 0], q1 = qb[f_ * 16 + 1], q2 = qb[f_ * 16 + 2],
               q3 = qb[f_ * 16 + 3], q4 = qb[f_ * 16 + 4], q5 = qb[f_ * 16 + 5],
               q6 = qb[f_ * 16 + 6], q7 = qb[f_ * 16 + 7];
        float acc0 = q0.x * kv0.x + q0.y * kv0.y + q0.z * kv0.z + q0.w * kv0.w;
        acc0 += q1.x * kv1.x + q1.y * kv1.y + q1.z * kv1.z + q1.w * kv1.w;
        acc0 += q2.x * kv2.x + q2.y * kv2.y + q2.z * kv2.z + q2.w * kv2.w;
        acc0 += q3.x * kv3.x + q3.y * kv3.y + q3.z * kv3.z + q3.w * kv3.w;
        acc0 += q4.x * kv4.x + q4.y * kv4.y + q4.z * kv4.z + q4.w * kv4.w;
        acc0 += q5.x * kv5.x + q5.y * kv5.y + q5.z * kv5.z + q5.w * kv5.w;
        acc0 += q6.x * kv6.x + q6.y * kv6.y + q6.z * kv6.z + q6.w * kv6.w;
        acc0 += q7.x * kv7.x + q7.y * kv7.y + q7.z * kv7.z + q7.w * kv7.w;
        s[f_] += acc0;
      }
    }
    float mx[8];
#pragma unroll
    for (int f_ = 0; f_ < 8; ++f_) mx[f_] = s[f_] * 0.125f;
#pragma unroll
    for (int f_ = 0; f_ < 8; ++f_) s[f_] = mx[f_];
#pragma unroll
    for (int st = 1; st < 64; st <<= 1)
#pragma unroll
      for (int f_ = 0; f_ < 8; ++f_) mx[f_] = fmaxf(mx[f_], __shfl_xor(mx[f_], st, 64));
    float alpha[8], w[8], sum[8];
#pragma unroll
    for (int f_ = 0; f_ < 8; ++f_) {
      float mn = fmaxf(m[f_], mx[f_]);
      alpha[f_] = __expf(m[f_] - mn);
      w[f_] = __expf(s[f_] - mn);
      m[f_] = mn;
      sum[f_] = w[f_];
    }
#pragma unroll
    for (int st = 1; st < 64; st <<= 1)
#pragma unroll
      for (int f_ = 0; f_ < 8; ++f_) sum[f_] += __shfl_xor(sum[f_], st, 64);
#pragma unroll
    for (int f_ = 0; f_ < 8; ++f_) l[f_] = l[f_] * alpha[f_] + sum[f_];
    *(float4*)&w_lds[wv][lane * 8]     = make_float4(w[0], w[1], w[2], w[3]);
    *(float4*)&w_lds[wv][lane * 8 + 4] = make_float4(w[4], w[5], w[6], w[7]);
#pragma unroll
    for (int f_ = 0; f_ < 8; ++f_) acc[f_] *= alpha[f_];
    const float* vb = v + (size_t)pc * DMODEL + h * 64 + lane;
#pragma unroll 4
    for (int kk = 0; kk < 64; ++kk) {
      float vd = vb[(size_t)kk * DMODEL];
      float4 wa = *(const float4*)&w_lds[wv][kk * 8];
      float4 wb = *(const float4*)&w_lds[wv][kk * 8 + 4];
      acc[0] += wa.x * vd; acc[1] += wa.y * vd; acc[2] += wa.z * vd; acc[3] += wa.w * vd;
      acc[4] += wb.x * vd; acc[5] += wb.y * vd; acc[6] += wb.z * vd; acc[7] += wb.w * vd;
    }
  }

  for (int f_ = 0; f_ < nfull; ++f_) {
    size_t idx = ((size_t)f_ * NHEADS + h) * P + piece;
    if (lane == 0) { pm[idx] = m[f_]; pl[idx] = l[f_]; }
    pacc[idx * 64 + lane] = acc[f_];
  }
}

// Split-K pass 2: merge the P partials per (full-feature, head). Writes bf16.
__global__ __launch_bounds__(256) void attn_full_comb(
    const int* __restrict__ fullist, const int* __restrict__ nfullp,
    int P, const float* __restrict__ pm, const float* __restrict__ pl,
    const float* __restrict__ pacc, unsigned short* __restrict__ out) {
  const int fl = blockIdx.x, h = blockIdx.y;
  if (fl >= *nfullp) return;
  const int feat = fullist[fl];
  const int t = threadIdx.x, lane = t & 63, wv = t >> 6;
  const size_t base = ((size_t)fl * NHEADS + h) * P;

  __shared__ float s_pm[128];    // P <= 128
  __shared__ float s_sc[128];
  __shared__ float s_red[4];
  __shared__ float s_part[4][64];

  for (int sp = t; sp < P; sp += 256) s_pm[sp] = pm[base + sp];
  __syncthreads();
  float mloc = -1e30f;
  for (int sp = t; sp < P; sp += 256) mloc = fmaxf(mloc, s_pm[sp]);
#pragma unroll
  for (int st = 1; st < 64; st <<= 1) mloc = fmaxf(mloc, __shfl_xor(mloc, st, 64));
  if (lane == 0) s_red[wv] = mloc;
  __syncthreads();
  const float M = fmaxf(fmaxf(s_red[0], s_red[1]), fmaxf(s_red[2], s_red[3]));
  __syncthreads();
  float lloc = 0.f;
  for (int sp = t; sp < P; sp += 256) {
    float sc = __expf(s_pm[sp] - M);
    s_sc[sp] = sc;
    lloc += pl[base + sp] * sc;
  }
#pragma unroll
  for (int st = 1; st < 64; st <<= 1) lloc += __shfl_xor(lloc, st, 64);
  if (lane == 0) s_red[wv] = lloc;
  __syncthreads();
  const float Lt = s_red[0] + s_red[1] + s_red[2] + s_red[3];
  float At = 0.f;
  for (int sp = wv; sp < P; sp += 4)
    At += pacc[(base + sp) * 64 + lane] * s_sc[sp];
  s_part[wv][lane] = At;
  __syncthreads();
  if (wv == 0) {
    float tot = s_part[0][lane] + s_part[1][lane] + s_part[2][lane] + s_part[3][lane];
    out[(size_t)feat * DMODEL + h * 64 + lane] = bf16_1(tot / Lt);
  }
}

extern "C" void kernel_launch(void* const* d_in, const int* in_sizes, int n_in,
                              void* d_out, int out_size, void* d_ws, size_t ws_size,
                              hipStream_t stream) {
  const float* x_qk = (const float*)d_in[0];
  const float* x_v  = (const float*)d_in[1];
  const int* qm     = (const int*)d_in[2];
  const int* ids    = (const int*)d_in[3];
  const int* padp   = (const int*)d_in[4];
  const float* Wq = (const float*)d_in[5];
  const float* bq = (const float*)d_in[6];
  const float* Wk = (const float*)d_in[7];
  const float* bk = (const float*)d_in[8];
  const float* Wv = (const float*)d_in[9];
  const float* bv = (const float*)d_in[10];
  const float* Wo = (const float*)d_in[11];
  const float* bo = (const float*)d_in[12];

  const int n = in_sizes[0] / DMODEL;   // 8192
  const int f = out_size / DMODEL;      // 1024

  // ws: kf,vf,qf f32 | af bf16 | Wbf x4 | xqb,xvb bf16 | ints | split partials
  float* kf = (float*)d_ws;
  float* vf = kf + (size_t)n * DMODEL;
  float* qf = vf + (size_t)n * DMODEL;
  unsigned short* af = (unsigned short*)(qf + (size_t)f * DMODEL);
  unsigned short* wqb = af + (size_t)f * DMODEL;
  unsigned short* wkb = wqb + DMODEL * DMODEL;
  unsigned short* wvb = wkb + DMODEL * DMODEL;
  unsigned short* wob = wvb + DMODEL * DMODEL;
  unsigned short* xqb = wob + DMODEL * DMODEL;
  unsigned short* xvb = xqb + (size_t)n * DMODEL;
  int* left     = (int*)(xvb + (size_t)n * DMODEL);
  int* right    = left + f;
  int* nvalid   = right + f;
  int* fullrank = nvalid + f;
  int* fullist  = fullrank + f;
  int* nfull    = fullist + MAXFULL;
  size_t off_bytes = ((size_t)((char*)(nfull + 1) - (char*)d_ws) + 255) & ~(size_t)255;
  int P = 128;
  while (P > 16) {
    size_t need = (size_t)MAXFULL * NHEADS * P * 66 * sizeof(float);
    if (off_bytes + need <= ws_size && (n / P) % 64 == 0 && n % P == 0) break;
    P >>= 1;
  }
  float* pm = (float*)((char*)d_ws + off_bytes);
  float* pl = pm + (size_t)MAXFULL * NHEADS * P;
  float* pacc = pl + (size_t)MAXFULL * NHEADS * P;

  build_segments<<<1, 1024, 0, stream>>>(qm, ids, padp, n, f, left, right,
                                         nvalid, fullrank, fullist, nfull);
  convW<<<1152, 256, 0, stream>>>(Wq, Wk, Wv, Wo, (unsigned*)wqb, (unsigned*)wkb,
                                  (unsigned*)wvb, (unsigned*)wob, DMODEL * DMODEL);
  convX<<<2048, 256, 0, stream>>>(x_qk, x_v, (unsigned*)xqb, (unsigned*)xvb,
                                  n * DMODEL);

  const int TKV = 6 * (n / 128);   // 384 blocks/segment, (n/128)%8==0
  const int TF  = 6 * (f / 128);   // 48 blocks, f/128 == 8
  GSeg g0 = { xqb, wkb, bk, nullptr, kf, 0 };
  GSeg g1 = { xvb, wvb, bv, nullptr, vf, TKV };
  GSeg g2 = { xqb, wqb, bq, left,    qf, 2 * TKV };
  gemm128<<<2 * TKV + TF, 256, 0, stream>>>(g0, g1, g2);

  attn_seg<<<dim3(f / 4, NHEADS), 256, 0, stream>>>(qf, kf, vf, left, right,
                                                    nvalid, ids, padp, af);
  attn_full_part<<<NHEADS * P / 4, 256, 0, stream>>>(qf, kf, vf, fullist, nfull,
                                                     n, P, pm, pl, pacc);
  attn_full_comb<<<dim3(MAXFULL, NHEADS), 256, 0, stream>>>(fullist, nfull, P,
                                                            pm, pl, pacc, af);

  GSeg gout = { af, wob, bo, nullptr, (float*)d_out, 0 };
  GSeg gnull = { af, wob, bo, nullptr, (float*)d_out, 1 << 30 };
  gemm128<<<TF, 256, 0, stream>>>(gout, gnull, gnull);
}

// Round 3
// 228.189 us; speedup vs baseline: 1.0212x; 1.0180x over previous
//
#include <hip/hip_runtime.h>

#define DMODEL 768
#define NHEADS 12
#define MAXFULL 16
#define NSTEP 24   // DMODEL / 32

typedef __attribute__((ext_vector_type(8))) short short8;
typedef __attribute__((ext_vector_type(4))) float f32x4;

__device__ __forceinline__ unsigned pack2_bf16(float a, float b) {
  unsigned ua = __float_as_uint(a), ub = __float_as_uint(b);
  ua = (ua + 0x7fffu + ((ua >> 16) & 1u)) >> 16;
  ub = (ub + 0x7fffu + ((ub >> 16) & 1u)) & 0xffff0000u;
  return ua | ub;
}
__device__ __forceinline__ unsigned short bf16_1(float a) {
  unsigned ua = __float_as_uint(a);
  return (unsigned short)((ua + 0x7fffu + ((ua >> 16) & 1u)) >> 16);
}

// direct global->LDS DMA, 16 B per lane; LDS dest = wave-uniform base + lane*16
__device__ __forceinline__ void load16_lds(const void* g, void* l) {
  __builtin_amdgcn_global_load_lds(
      (const __attribute__((address_space(1))) unsigned int*)g,
      (__attribute__((address_space(3))) unsigned int*)l, 16, 0, 0);
}

// convert the 4 weight matrices f32 -> bf16 once
__global__ __launch_bounds__(256) void convW(const float* __restrict__ w0,
    const float* __restrict__ w1, const float* __restrict__ w2,
    const float* __restrict__ w3, unsigned* __restrict__ o0,
    unsigned* __restrict__ o1, unsigned* __restrict__ o2,
    unsigned* __restrict__ o3, int count) {
  const int nv = count >> 2;
  const float* src[4] = {w0, w1, w2, w3};
  unsigned* dst[4] = {o0, o1, o2, o3};
  for (int idx = blockIdx.x * 256 + threadIdx.x; idx < 4 * nv;
       idx += gridDim.x * 256) {
    int m = idx / nv, r = idx - m * nv;
    float4 v = ((const float4*)src[m])[r];
    dst[m][2 * r]     = pack2_bf16(v.x, v.y);
    dst[m][2 * r + 1] = pack2_bf16(v.z, v.w);
  }
}

// convert x_qk, x_v f32 -> bf16 once
__global__ __launch_bounds__(256) void convX(const float* __restrict__ x0,
    const float* __restrict__ x1, unsigned* __restrict__ o0,
    unsigned* __restrict__ o1, int count) {
  const int nv = count >> 2;
  for (int idx = blockIdx.x * 256 + threadIdx.x; idx < 2 * nv;
       idx += gridDim.x * 256) {
    int m = idx / nv, r = idx - m * nv;
    float4 v = m ? ((const float4*)x1)[r] : ((const float4*)x0)[r];
    unsigned* d = m ? o1 : o0;
    d[2 * r]     = pack2_bf16(v.x, v.y);
    d[2 * r + 1] = pack2_bf16(v.z, v.w);
  }
}

struct GSeg {
  const unsigned short* A;   // bf16 activations [*,768]
  const unsigned short* W;   // bf16 weights [col][k]
  const float* bias;
  const int* row_map;        // optional row gather
  float* C;                  // f32 out
  int base;                  // first flat block id of this segment (mult of 8)
};

// T2 swizzle (both-sides, rule #21): LDS dest stays linear (DMA constraint),
// the GLOBAL source k-chunk is permuted per lane so that LDS slot (row, cs)
// holds global chunk cs ^ ((row>>1)&3). Reader applies the same involution.
// Bank math: group(r) = (4r + c'(r)) mod 8 with c' = (r>>1)&3 -> all 8 groups
// x2 lanes = 2-way (free, m136) instead of 8-way.
__device__ __forceinline__ void stage_step(const GSeg& d, int k0, int arow0,
    int arow1, int wrow0, int wrow1, int skc, unsigned short* AsB,
    unsigned short* BsB, int woff) {
  load16_lds(d.A + (size_t)arow0 * DMODEL + k0 + skc, AsB + woff);
  load16_lds(d.A + (size_t)arow1 * DMODEL + k0 + skc, AsB + woff + 16 * 32);
  load16_lds(d.W + (size_t)wrow0 * DMODEL + k0 + skc, BsB + woff);
  load16_lds(d.W + (size_t)wrow1 * DMODEL + k0 + skc, BsB + woff + 16 * 32);
}

__device__ __forceinline__ void compute_step(const unsigned short* AsB,
    const unsigned short* BsB, int wm, int wn, int m16, int qx,
    f32x4 acc[4][4]) {
  short8 a[4], b[4];
#pragma unroll
  for (int i = 0; i < 4; ++i)
    a[i] = *(const short8*)&AsB[(wm + i * 16 + m16) * 32 + qx * 8];
#pragma unroll
  for (int j2 = 0; j2 < 4; ++j2)
    b[j2] = *(const short8*)&BsB[(wn + j2 * 16 + m16) * 32 + qx * 8];
  __builtin_amdgcn_s_setprio(1);
#pragma unroll
  for (int i = 0; i < 4; ++i)
#pragma unroll
    for (int j2 = 0; j2 < 4; ++j2)
      acc[i][j2] = __builtin_amdgcn_mfma_f32_16x16x32_bf16(a[i], b[j2], acc[i][j2], 0, 0, 0);
  __builtin_amdgcn_s_setprio(0);
}

// pipelined m97-style GEMM, up to 3 fused segments: 128x128 tile, BK=32,
// 3-deep LDS ring + counted vmcnt (T3/T4) + LDS chunk swizzle (T2) +
// setprio around MFMA (T5).
__global__ __launch_bounds__(256) void gemm128(GSeg g0, GSeg g1, GSeg g2) {
  __shared__ __attribute__((aligned(16))) unsigned short As[3][128 * 32];
  __shared__ __attribute__((aligned(16))) unsigned short Bs[3][128 * 32];
  const int t = threadIdx.x;
  const int id = blockIdx.x;
  const GSeg& d = (id >= g2.base) ? g2 : ((id >= g1.base) ? g1 : g0);
  const int lid = id - d.base;
  const int xcd = lid & 7, j = lid >> 3;
  const int bn = (j % 6) * 128;
  const int bm = ((j / 6) * 8 + xcd) * 128;
  const int lane = t & 63, wid = t >> 6;
  const int m16 = lane & 15, quad = lane >> 4;
  const int qx = quad ^ ((m16 >> 1) & 3);      // T2 reader involution
  const int wm = (wid >> 1) * 64, wn = (wid & 1) * 64;

  f32x4 acc[4][4];
#pragma unroll
  for (int i = 0; i < 4; ++i)
#pragma unroll
    for (int j2 = 0; j2 < 4; ++j2) acc[i][j2] = (f32x4){0.f, 0.f, 0.f, 0.f};

  // staging: wave wid covers tile rows [wid*32, wid*32+32), 16 rows per issue,
  // lane covers row +lane/4; k-chunk is T2-permuted: (lane&3) ^ ((lane>>3)&3)
  const int srow = wid * 32 + (lane >> 2);
  const int skc = ((lane & 3) ^ ((lane >> 3) & 3)) * 8;
  int arow0, arow1;
  if (d.row_map) {
    arow0 = d.row_map[bm + srow];
    arow1 = d.row_map[bm + srow + 16];
  } else {
    arow0 = bm + srow;
    arow1 = bm + srow + 16;
  }
  const int wrow0 = bn + srow, wrow1 = bn + srow + 16;
  const int woff = (wid * 32) * 32;

  // prologue: stage steps 0,1,2 into ring buffers 0,1,2 (12 loads/wave)
  stage_step(d, 0,  arow0, arow1, wrow0, wrow1, skc, &As[0][0], &Bs[0][0], woff);
  stage_step(d, 32, arow0, arow1, wrow0, wrow1, skc, &As[1][0], &Bs[1][0], woff);
  stage_step(d, 64, arow0, arow1, wrow0, wrow1, skc, &As[2][0], &Bs[2][0], woff);

#pragma unroll 1
  for (int g = 0; g < (NSTEP - 3) / 3; ++g) {   // steps 0..20, groups of 3
    const int t0 = g * 3;
#pragma unroll
    for (int u = 0; u < 3; ++u) {
      const int ts = t0 + u;
      asm volatile("s_waitcnt vmcnt(8)" ::: "memory");  // step ts's 4 loads done
      __builtin_amdgcn_s_barrier();                     // ... for ALL waves
      __builtin_amdgcn_sched_barrier(0);
      compute_step(&As[u][0], &Bs[u][0], wm, wn, m16, qx, acc);
      __builtin_amdgcn_s_barrier();                     // all waves done reading
      __builtin_amdgcn_sched_barrier(0);
      stage_step(d, (ts + 3) * 32, arow0, arow1, wrow0, wrow1, skc,
                 &As[u][0], &Bs[u][0], woff);
    }
  }
  // epilogue: steps 21,22,23 in buffers 0,1,2; drain 8 -> 4 -> 0
  asm volatile("s_waitcnt vmcnt(8)" ::: "memory");
  __builtin_amdgcn_s_barrier();
  __builtin_amdgcn_sched_barrier(0);
  compute_step(&As[0][0], &Bs[0][0], wm, wn, m16, qx, acc);
  asm volatile("s_waitcnt vmcnt(4)" ::: "memory");
  __builtin_amdgcn_s_barrier();
  __builtin_amdgcn_sched_barrier(0);
  compute_step(&As[1][0], &Bs[1][0], wm, wn, m16, qx, acc);
  asm volatile("s_waitcnt vmcnt(0)" ::: "memory");
  __builtin_amdgcn_s_barrier();
  __builtin_amdgcn_sched_barrier(0);
  compute_step(&As[2][0], &Bs[2][0], wm, wn, m16, qx, acc);

  // epilogue: C/D layout col=lane&15, row=quad*4+r (m89/m91)
  float bv[4]; int bcol[4];
#pragma unroll
  for (int j2 = 0; j2 < 4; ++j2) {
    bcol[j2] = bn + wn + j2 * 16 + m16;
    bv[j2] = d.bias[bcol[j2]];
  }
#pragma unroll
  for (int i = 0; i < 4; ++i) {
    const int rbase = bm + wm + i * 16 + quad * 4;
#pragma unroll
    for (int r = 0; r < 4; ++r) {
      const int row = rbase + r;
#pragma unroll
      for (int j2 = 0; j2 < 4; ++j2)
        d.C[(size_t)row * DMODEL + bcol[j2]] = acc[i][j2][r] + bv[j2];
    }
  }
}

// one block: prefix-scan query_mask -> left/right/nvalid per feature,
// plus compact list of fully-masked features (nvalid==0).
__global__ __launch_bounds__(1024) void build_segments(const int* __restrict__ qm,
    const int* __restrict__ ids, const int* __restrict__ padp,
    int n, int f, int* __restrict__ left, int* __restrict__ right,
    int* __restrict__ nvalid, int* __restrict__ fullrank,
    int* __restrict__ fullist, int* __restrict__ nfull) {
  __shared__ int cnt[1024];
  __shared__ int fullcnt;
  const int t = threadIdx.x;
  if (t == 0) fullcnt = 0;
  const int per = (n + 1023) >> 10;
  const int base = t * per;
  int c = 0;
  for (int i = 0; i < per; ++i) {
    int p = base + i;
    if (p < n && qm[p] != 0) ++c;
  }
  cnt[t] = c;
  __syncthreads();
  for (int off = 1; off < 1024; off <<= 1) {
    int v = (t >= off) ? cnt[t - off] : 0;
    __syncthreads();
    cnt[t] += v;
    __syncthreads();
  }
  int r = cnt[t] - c;  // exclusive prefix
  for (int i = 0; i < per; ++i) {
    int p = base + i;
    if (p < n && qm[p] != 0) {
      if (r < f) left[r] = p;
      ++r;
    }
  }
  __syncthreads();
  const int pad = *padp;
  for (int i = t; i < f; i += 1024) {
    int L0 = left[i];
    int R0 = (i + 1 < f) ? left[i + 1] : n;
    right[i] = R0;
    int cv = 0;
    for (int p = L0; p < R0; ++p) cv += (ids[p] != pad) ? 1 : 0;
    nvalid[i] = cv;
    if (cv == 0) {
      int rk = atomicAdd(&fullcnt, 1);
      if (rk < MAXFULL) { fullist[rk] = i; fullrank[i] = rk; }
      else fullrank[i] = -1;
    } else {
      fullrank[i] = -1;
    }
  }
  __syncthreads();
  if (t == 0) *nfull = (fullcnt < MAXFULL) ? fullcnt : MAXFULL;
}

__device__ __forceinline__ float allreduce64(float x) {
#pragma unroll
  for (int m = 1; m < 64; m <<= 1) x += __shfl_xor(x, m, 64);
  return x;
}

// normal features: segments are exactly CHUNK=8 keys for this problem ->
// fast path loads all 8 k/v rows in PARALLEL (one memory round-trip), then
// 8 batched butterfly reduces + one 8-wide softmax. Serial fallback for
// robustness if a segment length != 8.
__global__ __launch_bounds__(64) void attn_seg(const float* __restrict__ q,
    const float* __restrict__ k, const float* __restrict__ v,
    const int* __restrict__ left, const int* __restrict__ right,
    const int* __restrict__ nvalid, const int* __restrict__ ids,
    const int* __restrict__ padp, unsigned short* __restrict__ out) {
  const int feat = blockIdx.x, h = blockIdx.y, lane = threadIdx.x;
  if (nvalid[feat] == 0) return;  // handled by attn_full_*
  const int off = h * 64 + lane;
  const int pad = *padp;
  const float qv = q[(size_t)feat * DMODEL + off];
  const int L0 = left[feat], R0 = right[feat];
  if (R0 - L0 == 8) {
    float kv[8], vv[8], s[8];
    int live[8];
#pragma unroll
    for (int p = 0; p < 8; ++p) {
      kv[p] = k[(size_t)(L0 + p) * DMODEL + off];
      vv[p] = v[(size_t)(L0 + p) * DMODEL + off];
      live[p] = (ids[L0 + p] != pad);
    }
#pragma unroll
    for (int p = 0; p < 8; ++p) s[p] = qv * kv[p];
#pragma unroll
    for (int m_ = 1; m_ < 64; m_ <<= 1)
#pragma unroll
      for (int p = 0; p < 8; ++p) s[p] += __shfl_xor(s[p], m_, 64);
    float mx = -1e30f;
#pragma unroll
    for (int p = 0; p < 8; ++p) {
      s[p] = live[p] ? s[p] * 0.125f : -1e30f;
      mx = fmaxf(mx, s[p]);
    }
    float l = 0.f, acc = 0.f;
#pragma unroll
    for (int p = 0; p < 8; ++p) {
      float w = __expf(s[p] - mx);
      l += w;
      acc += w * vv[p];
    }
    out[(size_t)feat * DMODEL + off] = bf16_1(acc / l);
    return;
  }
  // fallback: online softmax, serial
  float m = -1e30f, l = 0.f, acc = 0.f;
  for (int p = L0; p < R0; ++p) {
    if (ids[p] == pad) continue;
    float s = allreduce64(qv * k[(size_t)p * DMODEL + off]) * 0.125f;
    float mn = fmaxf(m, s);
    float al = __expf(m - mn);
    float w = __expf(s - mn);
    l = l * al + w;
    acc = acc * al + w * v[(size_t)p * DMODEL + off];
    m = mn;
  }
  out[(size_t)feat * DMODEL + off] = bf16_1(acc / l);
}

// fully-masked features: uniform -10000 bias cancels in softmax -> full softmax
// over ALL n keys (pads included, cross-batch).
__global__ __launch_bounds__(256) void attn_full_part(const float* __restrict__ q,
    const float* __restrict__ k, const float* __restrict__ v,
    const int* __restrict__ fullist, const int* __restrict__ nfullp,
    int n, int P, float* __restrict__ pm, float* __restrict__ pl,
    float* __restrict__ pacc) {
  const int nfull = *nfullp;
  if (nfull == 0) return;
  const int t = threadIdx.x, lane = t & 63, wv = t >> 6;
  const int gw = blockIdx.x * 4 + wv;     // P % 4 == 0 -> block-uniform head
  const int h = gw / P, piece = gw - h * P;
  const int pk = n / P;                    // keys per piece (multiple of 64)

  __shared__ float q_lds[8 * 64];
  __shared__ float w_lds[4][64 * 8];       // [wave][key][feat], 32B-aligned rows

  for (int idx = t; idx < 8 * 64; idx += 256) {
    int fl = idx >> 6, d = idx & 63;
    q_lds[idx] = (fl < nfull) ? q[(size_t)fullist[fl] * DMODEL + h * 64 + d] : 0.f;
  }
  __syncthreads();

  float m[8], l[8], acc[8];
#pragma unroll
  for (int f_ = 0; f_ < 8; ++f_) { m[f_] = -1e30f; l[f_] = 0.f; acc[f_] = 0.f; }

  for (int c = 0; c < pk; c += 64) {
    const int pc = piece * pk + c;
    float s[8];
#pragma unroll
    for (int f_ = 0; f_ < 8; ++f_) s[f_] = 0.f;
    const float4* kp = (const float4*)(k + (size_t)(pc + lane) * DMODEL + h * 64);
#pragma unroll 1
    for (int g = 0; g < 2; ++g) {
      float4 kv0 = kp[g * 8 + 0], kv1 = kp[g * 8 + 1], kv2 = kp[g * 8 + 2],
             kv3 = kp[g * 8 + 3], kv4 = kp[g * 8 + 4], kv5 = kp[g * 8 + 5],
             kv6 = kp[g * 8 + 6], kv7 = kp[g * 8 + 7];
      const float4* qb = (const float4*)&q_lds[g * 32];
#pragma unroll
      for (int f_ = 0; f_ < 8; ++f_) {
        float4 q0 = qb[f_ * 16 + 0], q1 = qb[f_ * 16 + 1], q2 = qb[f_ * 16 + 2],
               q3 = qb[f_ * 16 + 3], q4 = qb[f_ * 16 + 4], q5 = qb[f_ * 16 + 5],
               q6 = qb[f_ * 16 + 6], q7 = qb[f_ * 16 + 7];
        float acc0 = q0.x * kv0.x + q0.y * kv0.y + q0.z * kv0.z + q0.w * kv0.w;
        acc0 += q1.x * kv1.x + q1.y * kv1.y + q1.z * kv1.z + q1.w * kv1.w;
        acc0 += q2.x * kv2.x + q2.y * kv2.y + q2.z * kv2.z + q2.w * kv2.w;
        acc0 += q3.x * kv3.x + q3.y * kv3.y + q3.z * kv3.z + q3.w * kv3.w;
        acc0 += q4.x * kv4.x + q4.y * kv4.y + q4.z * kv4.z + q4.w * kv4.w;
        acc0 += q5.x * kv5.x + q5.y * kv5.y + q5.z * kv5.z + q5.w * kv5.w;
        acc0 += q6.x * kv6.x + q6.y * kv6.y + q6.z * kv6.z + q6.w * kv6.w;
        acc0 += q7.x * kv7.x + q7.y * kv7.y + q7.z * kv7.z + q7.w * kv7.w;
        s[f_] += acc0;
      }
    }
    float mx[8];
#pragma unroll
    for (int f_ = 0; f_ < 8; ++f_) mx[f_] = s[f_] * 0.125f;
#pragma unroll
    for (int f_ = 0; f_ < 8; ++f_) s[f_] = mx[f_];
#pragma unroll
    for (int st = 1; st < 64; st <<= 1)
#pragma unroll
      for (int f_ = 0; f_ < 8; ++f_) mx[f_] = fmaxf(mx[f_], __shfl_xor(mx[f_], st, 64));
    float alpha[8], w[8], sum[8];
#pragma unroll
    for (int f_ = 0; f_ < 8; ++f_) {
      float mn = fmaxf(m[f_], mx[f_]);
      alpha[f_] = __expf(m[f_] - mn);
      w[f_] = __expf(s[f_] - mn);
      m[f_] = mn;
      sum[f_] = w[f_];
    }
#pragma unroll
    for (int st = 1; st < 64; st <<= 1)
#pragma unroll
      for (int f_ = 0; f_ < 8; ++f_) sum[f_] += __shfl_xor(sum[f_], st, 64);
#pragma unroll
    for (int f_ = 0; f_ < 8; ++f_) l[f_] = l[f_] * alpha[f_] + sum[f_];
    *(float4*)&w_lds[wv][lane * 8]     = make_float4(w[0], w[1], w[2], w[3]);
    *(float4*)&w_lds[wv][lane * 8 + 4] = make_float4(w[4], w[5], w[6], w[7]);
#pragma unroll
    for (int f_ = 0; f_ < 8; ++f_) acc[f_] *= alpha[f_];
    const float* vb = v + (size_t)pc * DMODEL + h * 64 + lane;
#pragma unroll 4
    for (int kk = 0; kk < 64; ++kk) {
      float vd = vb[(size_t)kk * DMODEL];
      float4 wa = *(const float4*)&w_lds[wv][kk * 8];
      float4 wb = *(const float4*)&w_lds[wv][kk * 8 + 4];
      acc[0] += wa.x * vd; acc[1] += wa.y * vd; acc[2] += wa.z * vd; acc[3] += wa.w * vd;
      acc[4] += wb.x * vd; acc[5] += wb.y * vd; acc[6] += wb.z * vd; acc[7] += wb.w * vd;
    }
  }

  for (int f_ = 0; f_ < nfull; ++f_) {
    size_t idx = ((size_t)f_ * NHEADS + h) * P + piece;
    if (lane == 0) { pm[idx] = m[f_]; pl[idx] = l[f_]; }
    pacc[idx * 64 + lane] = acc[f_];
  }
}

// Split-K pass 2: merge the P partials per (full-feature, head). Writes bf16.
__global__ __launch_bounds__(256) void attn_full_comb(
    const int* __restrict__ fullist, const int* __restrict__ nfullp,
    int P, const float* __restrict__ pm, const float* __restrict__ pl,
    const float* __restrict__ pacc, unsigned short* __restrict__ out) {
  const int fl = blockIdx.x, h = blockIdx.y;
  if (fl >= *nfullp) return;
  const int feat = fullist[fl];
  const int t = threadIdx.x, lane = t & 63, wv = t >> 6;
  const size_t base = ((size_t)fl * NHEADS + h) * P;

  __shared__ float s_pm[128];    // P <= 128
  __shared__ float s_sc[128];
  __shared__ float s_red[4];
  __shared__ float s_part[4][64];

  for (int sp = t; sp < P; sp += 256) s_pm[sp] = pm[base + sp];
  __syncthreads();
  float mloc = -1e30f;
  for (int sp = t; sp < P; sp += 256) mloc = fmaxf(mloc, s_pm[sp]);
#pragma unroll
  for (int st = 1; st < 64; st <<= 1) mloc = fmaxf(mloc, __shfl_xor(mloc, st, 64));
  if (lane == 0) s_red[wv] = mloc;
  __syncthreads();
  const float M = fmaxf(fmaxf(s_red[0], s_red[1]), fmaxf(s_red[2], s_red[3]));
  __syncthreads();
  float lloc = 0.f;
  for (int sp = t; sp < P; sp += 256) {
    float sc = __expf(s_pm[sp] - M);
    s_sc[sp] = sc;
    lloc += pl[base + sp] * sc;
  }
#pragma unroll
  for (int st = 1; st < 64; st <<= 1) lloc += __shfl_xor(lloc, st, 64);
  if (lane == 0) s_red[wv] = lloc;
  __syncthreads();
  const float Lt = s_red[0] + s_red[1] + s_red[2] + s_red[3];
  float At = 0.f;
  for (int sp = wv; sp < P; sp += 4)
    At += pacc[(base + sp) * 64 + lane] * s_sc[sp];
  s_part[wv][lane] = At;
  __syncthreads();
  if (wv == 0) {
    float tot = s_part[0][lane] + s_part[1][lane] + s_part[2][lane] + s_part[3][lane];
    out[(size_t)feat * DMODEL + h * 64 + lane] = bf16_1(tot / Lt);
  }
}

extern "C" void kernel_launch(void* const* d_in, const int* in_sizes, int n_in,
                              void* d_out, int out_size, void* d_ws, size_t ws_size,
                              hipStream_t stream) {
  const float* x_qk = (const float*)d_in[0];
  const float* x_v  = (const float*)d_in[1];
  const int* qm     = (const int*)d_in[2];
  const int* ids    = (const int*)d_in[3];
  const int* padp   = (const int*)d_in[4];
  const float* Wq = (const float*)d_in[5];
  const float* bq = (const float*)d_in[6];
  const float* Wk = (const float*)d_in[7];
  const float* bk = (const float*)d_in[8];
  const float* Wv = (const float*)d_in[9];
  const float* bv = (const float*)d_in[10];
  const float* Wo = (const float*)d_in[11];
  const float* bo = (const float*)d_in[12];

  const int n = in_sizes[0] / DMODEL;   // 8192
  const int f = out_size / DMODEL;      // 1024

  // ws: kf,vf,qf f32 | af bf16 | Wbf x4 | xqb,xvb bf16 | ints | split partials
  float* kf = (float*)d_ws;
  float* vf = kf + (size_t)n * DMODEL;
  float* qf = vf + (size_t)n * DMODEL;
  unsigned short* af = (unsigned short*)(qf + (size_t)f * DMODEL);
  unsigned short* wqb = af + (size_t)f * DMODEL;
  unsigned short* wkb = wqb + DMODEL * DMODEL;
  unsigned short* wvb = wkb + DMODEL * DMODEL;
  unsigned short* wob = wvb + DMODEL * DMODEL;
  unsigned short* xqb = wob + DMODEL * DMODEL;
  unsigned short* xvb = xqb + (size_t)n * DMODEL;
  int* left     = (int*)(xvb + (size_t)n * DMODEL);
  int* right    = left + f;
  int* nvalid   = right + f;
  int* fullrank = nvalid + f;
  int* fullist  = fullrank + f;
  int* nfull    = fullist + MAXFULL;
  size_t off_bytes = ((size_t)((char*)(nfull + 1) - (char*)d_ws) + 255) & ~(size_t)255;
  int P = 128;
  while (P > 16) {
    size_t need = (size_t)MAXFULL * NHEADS * P * 66 * sizeof(float);
    if (off_bytes + need <= ws_size && (n / P) % 64 == 0 && n % P == 0) break;
    P >>= 1;
  }
  float* pm = (float*)((char*)d_ws + off_bytes);
  float* pl = pm + (size_t)MAXFULL * NHEADS * P;
  float* pacc = pl + (size_t)MAXFULL * NHEADS * P;

  build_segments<<<1, 1024, 0, stream>>>(qm, ids, padp, n, f, left, right,
                                         nvalid, fullrank, fullist, nfull);
  convW<<<1152, 256, 0, stream>>>(Wq, Wk, Wv, Wo, (unsigned*)wqb, (unsigned*)wkb,
                                  (unsigned*)wvb, (unsigned*)wob, DMODEL * DMODEL);
  convX<<<2048, 256, 0, stream>>>(x_qk, x_v, (unsigned*)xqb, (unsigned*)xvb,
                                  n * DMODEL);

  const int TKV = 6 * (n / 128);   // 384 blocks/segment, (n/128)%8==0
  const int TF  = 6 * (f / 128);   // 48 blocks, f/128 == 8
  GSeg g0 = { xqb, wkb, bk, nullptr, kf, 0 };
  GSeg g1 = { xvb, wvb, bv, nullptr, vf, TKV };
  GSeg g2 = { xqb, wqb, bq, left,    qf, 2 * TKV };
  gemm128<<<2 * TKV + TF, 256, 0, stream>>>(g0, g1, g2);

  attn_seg<<<dim3(f, NHEADS), 64, 0, stream>>>(qf, kf, vf, left, right, nvalid,
                                               ids, padp, af);
  attn_full_part<<<NHEADS * P / 4, 256, 0, stream>>>(qf, kf, vf, fullist, nfull,
                                                     n, P, pm, pl, pacc);
  attn_full_comb<<<dim3(MAXFULL, NHEADS), 256, 0, stream>>>(fullist, nfull, P,
                                                            pm, pl, pacc, af);

  GSeg gout = { af, wob, bo, nullptr, (float*)d_out, 0 };
  GSeg gnull = { af, wob, bo, nullptr, (float*)d_out, 1 << 30 };
  gemm128<<<TF, 256, 0, stream>>>(gout, gnull, gnull);
}

// Round 4
// 224.722 us; speedup vs baseline: 1.0370x; 1.0154x over previous
//
#include <hip/hip_runtime.h>

#define DMODEL 768
#define NHEADS 12
#define MAXFULL 16
#define NSTEP 24   // DMODEL / 32

typedef __attribute__((ext_vector_type(8))) short short8;
typedef __attribute__((ext_vector_type(4))) float f32x4;

__device__ __forceinline__ unsigned pack2_bf16(float a, float b) {
  unsigned ua = __float_as_uint(a), ub = __float_as_uint(b);
  ua = (ua + 0x7fffu + ((ua >> 16) & 1u)) >> 16;
  ub = (ub + 0x7fffu + ((ub >> 16) & 1u)) & 0xffff0000u;
  return ua | ub;
}
__device__ __forceinline__ unsigned short bf16_1(float a) {
  unsigned ua = __float_as_uint(a);
  return (unsigned short)((ua + 0x7fffu + ((ua >> 16) & 1u)) >> 16);
}

// direct global->LDS DMA, 16 B per lane; LDS dest = wave-uniform base + lane*16
__device__ __forceinline__ void load16_lds(const void* g, void* l) {
  __builtin_amdgcn_global_load_lds(
      (const __attribute__((address_space(1))) unsigned int*)g,
      (__attribute__((address_space(3))) unsigned int*)l, 16, 0, 0);
}

// fused f32->bf16 conversion: 4 weight matrices + x_qk + x_v, one launch
__global__ __launch_bounds__(256) void convAll(const float* __restrict__ w0,
    const float* __restrict__ w1, const float* __restrict__ w2,
    const float* __restrict__ w3, unsigned* __restrict__ o0,
    unsigned* __restrict__ o1, unsigned* __restrict__ o2,
    unsigned* __restrict__ o3, int wcount,
    const float* __restrict__ x0, const float* __restrict__ x1,
    unsigned* __restrict__ xo0, unsigned* __restrict__ xo1, int xcount) {
  const int nvw = wcount >> 2;
  const float* src[4] = {w0, w1, w2, w3};
  unsigned* dst[4] = {o0, o1, o2, o3};
  for (int idx = blockIdx.x * 256 + threadIdx.x; idx < 4 * nvw;
       idx += gridDim.x * 256) {
    int m = idx / nvw, r = idx - m * nvw;
    float4 v = ((const float4*)src[m])[r];
    dst[m][2 * r]     = pack2_bf16(v.x, v.y);
    dst[m][2 * r + 1] = pack2_bf16(v.z, v.w);
  }
  const int nvx = xcount >> 2;
  for (int idx = blockIdx.x * 256 + threadIdx.x; idx < 2 * nvx;
       idx += gridDim.x * 256) {
    int m = idx / nvx, r = idx - m * nvx;
    float4 v = m ? ((const float4*)x1)[r] : ((const float4*)x0)[r];
    unsigned* d = m ? xo1 : xo0;
    d[2 * r]     = pack2_bf16(v.x, v.y);
    d[2 * r + 1] = pack2_bf16(v.z, v.w);
  }
}

struct GSeg {
  const unsigned short* A;   // bf16 activations [*,768]
  const unsigned short* W;   // bf16 weights [col][k]
  const float* bias;
  const int* row_map;        // optional row gather
  float* C;                  // f32 out
  int base;                  // first flat block id of this segment (mult of 8)
};

// T2 swizzle (both-sides, rule #21): LDS dest stays linear (DMA constraint),
// the GLOBAL source k-chunk is permuted per lane so that LDS slot (row, cs)
// holds global chunk cs ^ ((row>>1)&3). Reader applies the same involution.
__device__ __forceinline__ void stage_step(const GSeg& d, int k0, int arow0,
    int arow1, int wrow0, int wrow1, int skc, unsigned short* AsB,
    unsigned short* BsB, int woff) {
  load16_lds(d.A + (size_t)arow0 * DMODEL + k0 + skc, AsB + woff);
  load16_lds(d.A + (size_t)arow1 * DMODEL + k0 + skc, AsB + woff + 16 * 32);
  load16_lds(d.W + (size_t)wrow0 * DMODEL + k0 + skc, BsB + woff);
  load16_lds(d.W + (size_t)wrow1 * DMODEL + k0 + skc, BsB + woff + 16 * 32);
}

__device__ __forceinline__ void compute_step(const unsigned short* AsB,
    const unsigned short* BsB, int wm, int wn, int m16, int qx,
    f32x4 acc[4][4]) {
  short8 a[4], b[4];
#pragma unroll
  for (int i = 0; i < 4; ++i)
    a[i] = *(const short8*)&AsB[(wm + i * 16 + m16) * 32 + qx * 8];
#pragma unroll
  for (int j2 = 0; j2 < 4; ++j2)
    b[j2] = *(const short8*)&BsB[(wn + j2 * 16 + m16) * 32 + qx * 8];
  __builtin_amdgcn_s_setprio(1);
#pragma unroll
  for (int i = 0; i < 4; ++i)
#pragma unroll
    for (int j2 = 0; j2 < 4; ++j2)
      acc[i][j2] = __builtin_amdgcn_mfma_f32_16x16x32_bf16(a[i], b[j2], acc[i][j2], 0, 0, 0);
  __builtin_amdgcn_s_setprio(0);
}

// pipelined m97-style GEMM, up to 3 fused segments: 128x128 tile, BK=32,
// 4-deep LDS ring + counted vmcnt(12) (T3/T4): lookahead 3 steps (~750+ cy)
// covers HBM latency (~900 cy); 64 KB LDS -> 2 blocks/CU for cross-block
// interleave. T2 chunk swizzle + T5 setprio retained.
__global__ __launch_bounds__(256) void gemm128(GSeg g0, GSeg g1, GSeg g2) {
  __shared__ __attribute__((aligned(16))) unsigned short As[4][128 * 32];
  __shared__ __attribute__((aligned(16))) unsigned short Bs[4][128 * 32];
  const int t = threadIdx.x;
  const int id = blockIdx.x;
  const GSeg& d = (id >= g2.base) ? g2 : ((id >= g1.base) ? g1 : g0);
  const int lid = id - d.base;
  const int xcd = lid & 7, j = lid >> 3;
  const int bn = (j % 6) * 128;
  const int bm = ((j / 6) * 8 + xcd) * 128;
  const int lane = t & 63, wid = t >> 6;
  const int m16 = lane & 15, quad = lane >> 4;
  const int qx = quad ^ ((m16 >> 1) & 3);      // T2 reader involution
  const int wm = (wid >> 1) * 64, wn = (wid & 1) * 64;

  f32x4 acc[4][4];
#pragma unroll
  for (int i = 0; i < 4; ++i)
#pragma unroll
    for (int j2 = 0; j2 < 4; ++j2) acc[i][j2] = (f32x4){0.f, 0.f, 0.f, 0.f};

  // staging: wave wid covers tile rows [wid*32, wid*32+32), 16 rows per issue,
  // lane covers row +lane/4; k-chunk is T2-permuted: (lane&3) ^ ((lane>>3)&3)
  const int srow = wid * 32 + (lane >> 2);
  const int skc = ((lane & 3) ^ ((lane >> 3) & 3)) * 8;
  int arow0, arow1;
  if (d.row_map) {
    arow0 = d.row_map[bm + srow];
    arow1 = d.row_map[bm + srow + 16];
  } else {
    arow0 = bm + srow;
    arow1 = bm + srow + 16;
  }
  const int wrow0 = bn + srow, wrow1 = bn + srow + 16;
  const int woff = (wid * 32) * 32;

  // prologue: stage steps 0..3 into ring buffers 0..3 (16 loads/wave)
  stage_step(d, 0,  arow0, arow1, wrow0, wrow1, skc, &As[0][0], &Bs[0][0], woff);
  stage_step(d, 32, arow0, arow1, wrow0, wrow1, skc, &As[1][0], &Bs[1][0], woff);
  stage_step(d, 64, arow0, arow1, wrow0, wrow1, skc, &As[2][0], &Bs[2][0], woff);
  stage_step(d, 96, arow0, arow1, wrow0, wrow1, skc, &As[3][0], &Bs[3][0], woff);

#pragma unroll 1
  for (int g = 0; g < (NSTEP - 4) / 4; ++g) {   // steps 0..19, groups of 4
    const int t0 = g * 4;
#pragma unroll
    for (int u = 0; u < 4; ++u) {
      const int ts = t0 + u;
      asm volatile("s_waitcnt vmcnt(12)" ::: "memory");  // step ts's loads done
      __builtin_amdgcn_s_barrier();                      // ... for ALL waves
      __builtin_amdgcn_sched_barrier(0);
      compute_step(&As[u][0], &Bs[u][0], wm, wn, m16, qx, acc);
      __builtin_amdgcn_s_barrier();                      // all waves done reading
      __builtin_amdgcn_sched_barrier(0);
      stage_step(d, (ts + 4) * 32, arow0, arow1, wrow0, wrow1, skc,
                 &As[u][0], &Bs[u][0], woff);
    }
  }
  // epilogue: steps 20..23 in buffers 0..3; drain 12 -> 8 -> 4 -> 0
  asm volatile("s_waitcnt vmcnt(12)" ::: "memory");
  __builtin_amdgcn_s_barrier();
  __builtin_amdgcn_sched_barrier(0);
  compute_step(&As[0][0], &Bs[0][0], wm, wn, m16, qx, acc);
  asm volatile("s_waitcnt vmcnt(8)" ::: "memory");
  __builtin_amdgcn_s_barrier();
  __builtin_amdgcn_sched_barrier(0);
  compute_step(&As[1][0], &Bs[1][0], wm, wn, m16, qx, acc);
  asm volatile("s_waitcnt vmcnt(4)" ::: "memory");
  __builtin_amdgcn_s_barrier();
  __builtin_amdgcn_sched_barrier(0);
  compute_step(&As[2][0], &Bs[2][0], wm, wn, m16, qx, acc);
  asm volatile("s_waitcnt vmcnt(0)" ::: "memory");
  __builtin_amdgcn_s_barrier();
  __builtin_amdgcn_sched_barrier(0);
  compute_step(&As[3][0], &Bs[3][0], wm, wn, m16, qx, acc);

  // epilogue: C/D layout col=lane&15, row=quad*4+r (m89/m91)
  float bv[4]; int bcol[4];
#pragma unroll
  for (int j2 = 0; j2 < 4; ++j2) {
    bcol[j2] = bn + wn + j2 * 16 + m16;
    bv[j2] = d.bias[bcol[j2]];
  }
#pragma unroll
  for (int i = 0; i < 4; ++i) {
    const int rbase = bm + wm + i * 16 + quad * 4;
#pragma unroll
    for (int r = 0; r < 4; ++r) {
      const int row = rbase + r;
#pragma unroll
      for (int j2 = 0; j2 < 4; ++j2)
        d.C[(size_t)row * DMODEL + bcol[j2]] = acc[i][j2][r] + bv[j2];
    }
  }
}

// one block: prefix-scan query_mask -> left/right/nvalid per feature,
// plus compact list of fully-masked features (nvalid==0).
__global__ __launch_bounds__(1024) void build_segments(const int* __restrict__ qm,
    const int* __restrict__ ids, const int* __restrict__ padp,
    int n, int f, int* __restrict__ left, int* __restrict__ right,
    int* __restrict__ nvalid, int* __restrict__ fullrank,
    int* __restrict__ fullist, int* __restrict__ nfull) {
  __shared__ int cnt[1024];
  __shared__ int fullcnt;
  const int t = threadIdx.x;
  if (t == 0) fullcnt = 0;
  const int per = (n + 1023) >> 10;
  const int base = t * per;
  int c = 0;
  for (int i = 0; i < per; ++i) {
    int p = base + i;
    if (p < n && qm[p] != 0) ++c;
  }
  cnt[t] = c;
  __syncthreads();
  for (int off = 1; off < 1024; off <<= 1) {
    int v = (t >= off) ? cnt[t - off] : 0;
    __syncthreads();
    cnt[t] += v;
    __syncthreads();
  }
  int r = cnt[t] - c;  // exclusive prefix
  for (int i = 0; i < per; ++i) {
    int p = base + i;
    if (p < n && qm[p] != 0) {
      if (r < f) left[r] = p;
      ++r;
    }
  }
  __syncthreads();
  const int pad = *padp;
  for (int i = t; i < f; i += 1024) {
    int L0 = left[i];
    int R0 = (i + 1 < f) ? left[i + 1] : n;
    right[i] = R0;
    int cv = 0;
    for (int p = L0; p < R0; ++p) cv += (ids[p] != pad) ? 1 : 0;
    nvalid[i] = cv;
    if (cv == 0) {
      int rk = atomicAdd(&fullcnt, 1);
      if (rk < MAXFULL) { fullist[rk] = i; fullrank[i] = rk; }
      else fullrank[i] = -1;
    } else {
      fullrank[i] = -1;
    }
  }
  __syncthreads();
  if (t == 0) *nfull = (fullcnt < MAXFULL) ? fullcnt : MAXFULL;
}

__device__ __forceinline__ float allreduce64(float x) {
#pragma unroll
  for (int m = 1; m < 64; m <<= 1) x += __shfl_xor(x, m, 64);
  return x;
}

// normal features: segments are exactly CHUNK=8 keys for this problem ->
// fast path loads all 8 k/v rows in PARALLEL (one memory round-trip), then
// 8 batched butterfly reduces + one 8-wide softmax. Serial fallback for
// robustness if a segment length != 8.
__global__ __launch_bounds__(64) void attn_seg(const float* __restrict__ q,
    const float* __restrict__ k, const float* __restrict__ v,
    const int* __restrict__ left, const int* __restrict__ right,
    const int* __restrict__ nvalid, const int* __restrict__ ids,
    const int* __restrict__ padp, unsigned short* __restrict__ out) {
  const int feat = blockIdx.x, h = blockIdx.y, lane = threadIdx.x;
  if (nvalid[feat] == 0) return;  // handled by attn_full_*
  const int off = h * 64 + lane;
  const int pad = *padp;
  const float qv = q[(size_t)feat * DMODEL + off];
  const int L0 = left[feat], R0 = right[feat];
  if (R0 - L0 == 8) {
    float kv[8], vv[8], s[8];
    int live[8];
#pragma unroll
    for (int p = 0; p < 8; ++p) {
      kv[p] = k[(size_t)(L0 + p) * DMODEL + off];
      vv[p] = v[(size_t)(L0 + p) * DMODEL + off];
      live[p] = (ids[L0 + p] != pad);
    }
#pragma unroll
    for (int p = 0; p < 8; ++p) s[p] = qv * kv[p];
#pragma unroll
    for (int m_ = 1; m_ < 64; m_ <<= 1)
#pragma unroll
      for (int p = 0; p < 8; ++p) s[p] += __shfl_xor(s[p], m_, 64);
    float mx = -1e30f;
#pragma unroll
    for (int p = 0; p < 8; ++p) {
      s[p] = live[p] ? s[p] * 0.125f : -1e30f;
      mx = fmaxf(mx, s[p]);
    }
    float l = 0.f, acc = 0.f;
#pragma unroll
    for (int p = 0; p < 8; ++p) {
      float w = __expf(s[p] - mx);
      l += w;
      acc += w * vv[p];
    }
    out[(size_t)feat * DMODEL + off] = bf16_1(acc / l);
    return;
  }
  // fallback: online softmax, serial
  float m = -1e30f, l = 0.f, acc = 0.f;
  for (int p = L0; p < R0; ++p) {
    if (ids[p] == pad) continue;
    float s = allreduce64(qv * k[(size_t)p * DMODEL + off]) * 0.125f;
    float mn = fmaxf(m, s);
    float al = __expf(m - mn);
    float w = __expf(s - mn);
    l = l * al + w;
    acc = acc * al + w * v[(size_t)p * DMODEL + off];
    m = mn;
  }
  out[(size_t)feat * DMODEL + off] = bf16_1(acc / l);
}

// fully-masked features: uniform -10000 bias cancels in softmax -> full softmax
// over ALL n keys (pads included, cross-batch).
__global__ __launch_bounds__(256) void attn_full_part(const float* __restrict__ q,
    const float* __restrict__ k, const float* __restrict__ v,
    const int* __restrict__ fullist, const int* __restrict__ nfullp,
    int n, int P, float* __restrict__ pm, float* __restrict__ pl,
    float* __restrict__ pacc) {
  const int nfull = *nfullp;
  if (nfull == 0) return;
  const int t = threadIdx.x, lane = t & 63, wv = t >> 6;
  const int gw = blockIdx.x * 4 + wv;     // P % 4 == 0 -> block-uniform head
  const int h = gw / P, piece = gw - h * P;
  const int pk = n / P;                    // keys per piece (multiple of 64)

  __shared__ float q_lds[8 * 64];
  __shared__ float w_lds[4][64 * 8];       // [wave][key][feat], 32B-aligned rows

  for (int idx = t; idx < 8 * 64; idx += 256) {
    int fl = idx >> 6, d = idx & 63;
    q_lds[idx] = (fl < nfull) ? q[(size_t)fullist[fl] * DMODEL + h * 64 + d] : 0.f;
  }
  __syncthreads();

  float m[8], l[8], acc[8];
#pragma unroll
  for (int f_ = 0; f_ < 8; ++f_) { m[f_] = -1e30f; l[f_] = 0.f; acc[f_] = 0.f; }

  for (int c = 0; c < pk; c += 64) {
    const int pc = piece * pk + c;
    float s[8];
#pragma unroll
    for (int f_ = 0; f_ < 8; ++f_) s[f_] = 0.f;
    const float4* kp = (const float4*)(k + (size_t)(pc + lane) * DMODEL + h * 64);
#pragma unroll 1
    for (int g = 0; g < 2; ++g) {
      float4 kv0 = kp[g * 8 + 0], kv1 = kp[g * 8 + 1], kv2 = kp[g * 8 + 2],
             kv3 = kp[g * 8 + 3], kv4 = kp[g * 8 + 4], kv5 = kp[g * 8 + 5],
             kv6 = kp[g * 8 + 6], kv7 = kp[g * 8 + 7];
      const float4* qb = (const float4*)&q_lds[g * 32];
#pragma unroll
      for (int f_ = 0; f_ < 8; ++f_) {
        float4 q0 = qb[f_ * 16 + 0], q1 = qb[f_ * 16 + 1], q2 = qb[f_ * 16 + 2],
               q3 = qb[f_ * 16 + 3], q4 = qb[f_ * 16 + 4], q5 = qb[f_ * 16 + 5],
               q6 = qb[f_ * 16 + 6], q7 = qb[f_ * 16 + 7];
        float acc0 = q0.x * kv0.x + q0.y * kv0.y + q0.z * kv0.z + q0.w * kv0.w;
        acc0 += q1.x * kv1.x + q1.y * kv1.y + q1.z * kv1.z + q1.w * kv1.w;
        acc0 += q2.x * kv2.x + q2.y * kv2.y + q2.z * kv2.z + q2.w * kv2.w;
        acc0 += q3.x * kv3.x + q3.y * kv3.y + q3.z * kv3.z + q3.w * kv3.w;
        acc0 += q4.x * kv4.x + q4.y * kv4.y + q4.z * kv4.z + q4.w * kv4.w;
        acc0 += q5.x * kv5.x + q5.y * kv5.y + q5.z * kv5.z + q5.w * kv5.w;
        acc0 += q6.x * kv6.x + q6.y * kv6.y + q6.z * kv6.z + q6.w * kv6.w;
        acc0 += q7.x * kv7.x + q7.y * kv7.y + q7.z * kv7.z + q7.w * kv7.w;
        s[f_] += acc0;
      }
    }
    float mx[8];
#pragma unroll
    for (int f_ = 0; f_ < 8; ++f_) mx[f_] = s[f_] * 0.125f;
#pragma unroll
    for (int f_ = 0; f_ < 8; ++f_) s[f_] = mx[f_];
#pragma unroll
    for (int st = 1; st < 64; st <<= 1)
#pragma unroll
      for (int f_ = 0; f_ < 8; ++f_) mx[f_] = fmaxf(mx[f_], __shfl_xor(mx[f_], st, 64));
    float alpha[8], w[8], sum[8];
#pragma unroll
    for (int f_ = 0; f_ < 8; ++f_) {
      float mn = fmaxf(m[f_], mx[f_]);
      alpha[f_] = __expf(m[f_] - mn);
      w[f_] = __expf(s[f_] - mn);
      m[f_] = mn;
      sum[f_] = w[f_];
    }
#pragma unroll
    for (int st = 1; st < 64; st <<= 1)
#pragma unroll
      for (int f_ = 0; f_ < 8; ++f_) sum[f_] += __shfl_xor(sum[f_], st, 64);
#pragma unroll
    for (int f_ = 0; f_ < 8; ++f_) l[f_] = l[f_] * alpha[f_] + sum[f_];
    *(float4*)&w_lds[wv][lane * 8]     = make_float4(w[0], w[1], w[2], w[3]);
    *(float4*)&w_lds[wv][lane * 8 + 4] = make_float4(w[4], w[5], w[6], w[7]);
#pragma unroll
    for (int f_ = 0; f_ < 8; ++f_) acc[f_] *= alpha[f_];
    const float* vb = v + (size_t)pc * DMODEL + h * 64 + lane;
#pragma unroll 4
    for (int kk = 0; kk < 64; ++kk) {
      float vd = vb[(size_t)kk * DMODEL];
      float4 wa = *(const float4*)&w_lds[wv][kk * 8];
      float4 wb = *(const float4*)&w_lds[wv][kk * 8 + 4];
      acc[0] += wa.x * vd; acc[1] += wa.y * vd; acc[2] += wa.z * vd; acc[3] += wa.w * vd;
      acc[4] += wb.x * vd; acc[5] += wb.y * vd; acc[6] += wb.z * vd; acc[7] += wb.w * vd;
    }
  }

  for (int f_ = 0; f_ < nfull; ++f_) {
    size_t idx = ((size_t)f_ * NHEADS + h) * P + piece;
    if (lane == 0) { pm[idx] = m[f_]; pl[idx] = l[f_]; }
    pacc[idx * 64 + lane] = acc[f_];
  }
}

// Split-K pass 2: merge the P partials per (full-feature, head). Writes bf16.
__global__ __launch_bounds__(256) void attn_full_comb(
    const int* __restrict__ fullist, const int* __restrict__ nfullp,
    int P, const float* __restrict__ pm, const float* __restrict__ pl,
    const float* __restrict__ pacc, unsigned short* __restrict__ out) {
  const int fl = blockIdx.x, h = blockIdx.y;
  if (fl >= *nfullp) return;
  const int feat = fullist[fl];
  const int t = threadIdx.x, lane = t & 63, wv = t >> 6;
  const size_t base = ((size_t)fl * NHEADS + h) * P;

  __shared__ float s_pm[128];    // P <= 128
  __shared__ float s_sc[128];
  __shared__ float s_red[4];
  __shared__ float s_part[4][64];

  for (int sp = t; sp < P; sp += 256) s_pm[sp] = pm[base + sp];
  __syncthreads();
  float mloc = -1e30f;
  for (int sp = t; sp < P; sp += 256) mloc = fmaxf(mloc, s_pm[sp]);
#pragma unroll
  for (int st = 1; st < 64; st <<= 1) mloc = fmaxf(mloc, __shfl_xor(mloc, st, 64));
  if (lane == 0) s_red[wv] = mloc;
  __syncthreads();
  const float M = fmaxf(fmaxf(s_red[0], s_red[1]), fmaxf(s_red[2], s_red[3]));
  __syncthreads();
  float lloc = 0.f;
  for (int sp = t; sp < P; sp += 256) {
    float sc = __expf(s_pm[sp] - M);
    s_sc[sp] = sc;
    lloc += pl[base + sp] * sc;
  }
#pragma unroll
  for (int st = 1; st < 64; st <<= 1) lloc += __shfl_xor(lloc, st, 64);
  if (lane == 0) s_red[wv] = lloc;
  __syncthreads();
  const float Lt = s_red[0] + s_red[1] + s_red[2] + s_red[3];
  float At = 0.f;
  for (int sp = wv; sp < P; sp += 4)
    At += pacc[(base + sp) * 64 + lane] * s_sc[sp];
  s_part[wv][lane] = At;
  __syncthreads();
  if (wv == 0) {
    float tot = s_part[0][lane] + s_part[1][lane] + s_part[2][lane] + s_part[3][lane];
    out[(size_t)feat * DMODEL + h * 64 + lane] = bf16_1(tot / Lt);
  }
}

extern "C" void kernel_launch(void* const* d_in, const int* in_sizes, int n_in,
                              void* d_out, int out_size, void* d_ws, size_t ws_size,
                              hipStream_t stream) {
  const float* x_qk = (const float*)d_in[0];
  const float* x_v  = (const float*)d_in[1];
  const int* qm     = (const int*)d_in[2];
  const int* ids    = (const int*)d_in[3];
  const int* padp   = (const int*)d_in[4];
  const float* Wq = (const float*)d_in[5];
  const float* bq = (const float*)d_in[6];
  const float* Wk = (const float*)d_in[7];
  const float* bk = (const float*)d_in[8];
  const float* Wv = (const float*)d_in[9];
  const float* bv = (const float*)d_in[10];
  const float* Wo = (const float*)d_in[11];
  const float* bo = (const float*)d_in[12];

  const int n = in_sizes[0] / DMODEL;   // 8192
  const int f = out_size / DMODEL;      // 1024

  // ws: kf,vf,qf f32 | af bf16 | Wbf x4 | xqb,xvb bf16 | ints | split partials
  float* kf = (float*)d_ws;
  float* vf = kf + (size_t)n * DMODEL;
  float* qf = vf + (size_t)n * DMODEL;
  unsigned short* af = (unsigned short*)(qf + (size_t)f * DMODEL);
  unsigned short* wqb = af + (size_t)f * DMODEL;
  unsigned short* wkb = wqb + DMODEL * DMODEL;
  unsigned short* wvb = wkb + DMODEL * DMODEL;
  unsigned short* wob = wvb + DMODEL * DMODEL;
  unsigned short* xqb = wob + DMODEL * DMODEL;
  unsigned short* xvb = xqb + (size_t)n * DMODEL;
  int* left     = (int*)(xvb + (size_t)n * DMODEL);
  int* right    = left + f;
  int* nvalid   = right + f;
  int* fullrank = nvalid + f;
  int* fullist  = fullrank + f;
  int* nfull    = fullist + MAXFULL;
  size_t off_bytes = ((size_t)((char*)(nfull + 1) - (char*)d_ws) + 255) & ~(size_t)255;
  int P = 128;
  while (P > 16) {
    size_t need = (size_t)MAXFULL * NHEADS * P * 66 * sizeof(float);
    if (off_bytes + need <= ws_size && (n / P) % 64 == 0 && n % P == 0) break;
    P >>= 1;
  }
  float* pm = (float*)((char*)d_ws + off_bytes);
  float* pl = pm + (size_t)MAXFULL * NHEADS * P;
  float* pacc = pl + (size_t)MAXFULL * NHEADS * P;

  build_segments<<<1, 1024, 0, stream>>>(qm, ids, padp, n, f, left, right,
                                         nvalid, fullrank, fullist, nfull);
  convAll<<<2048, 256, 0, stream>>>(Wq, Wk, Wv, Wo, (unsigned*)wqb,
                                    (unsigned*)wkb, (unsigned*)wvb,
                                    (unsigned*)wob, DMODEL * DMODEL,
                                    x_qk, x_v, (unsigned*)xqb, (unsigned*)xvb,
                                    n * DMODEL);

  const int TKV = 6 * (n / 128);   // 384 blocks/segment, (n/128)%8==0
  const int TF  = 6 * (f / 128);   // 48 blocks, f/128 == 8
  GSeg g0 = { xqb, wkb, bk, nullptr, kf, 0 };
  GSeg g1 = { xvb, wvb, bv, nullptr, vf, TKV };
  GSeg g2 = { xqb, wqb, bq, left,    qf, 2 * TKV };
  gemm128<<<2 * TKV + TF, 256, 0, stream>>>(g0, g1, g2);

  attn_seg<<<dim3(f, NHEADS), 64, 0, stream>>>(qf, kf, vf, left, right, nvalid,
                                               ids, padp, af);
  attn_full_part<<<NHEADS * P / 4, 256, 0, stream>>>(qf, kf, vf, fullist, nfull,
                                                     n, P, pm, pl, pacc);
  attn_full_comb<<<dim3(MAXFULL, NHEADS), 256, 0, stream>>>(fullist, nfull, P,
                                                            pm, pl, pacc, af);

  GSeg gout = { af, wob, bo, nullptr, (float*)d_out, 0 };
  GSeg gnull = { af, wob, bo, nullptr, (float*)d_out, 1 << 30 };
  gemm128<<<TF, 256, 0, stream>>>(gout, gnull, gnull);
}

// Round 5
// 219.186 us; speedup vs baseline: 1.0632x; 1.0253x over previous
//
#include <hip/hip_runtime.h>

#define DMODEL 768
#define NHEADS 12
#define MAXFULL 16
#define NSTEP 24   // DMODEL / 32

typedef __attribute__((ext_vector_type(8))) short short8;
typedef __attribute__((ext_vector_type(4))) float f32x4;

__device__ __forceinline__ unsigned pack2_bf16(float a, float b) {
  unsigned ua = __float_as_uint(a), ub = __float_as_uint(b);
  ua = (ua + 0x7fffu + ((ua >> 16) & 1u)) >> 16;
  ub = (ub + 0x7fffu + ((ub >> 16) & 1u)) & 0xffff0000u;
  return ua | ub;
}
__device__ __forceinline__ unsigned short bf16_1(float a) {
  unsigned ua = __float_as_uint(a);
  return (unsigned short)((ua + 0x7fffu + ((ua >> 16) & 1u)) >> 16);
}

// direct global->LDS DMA, 16 B per lane; LDS dest = wave-uniform base + lane*16
__device__ __forceinline__ void load16_lds(const void* g, void* l) {
  __builtin_amdgcn_global_load_lds(
      (const __attribute__((address_space(1))) unsigned int*)g,
      (__attribute__((address_space(3))) unsigned int*)l, 16, 0, 0);
}

// fused f32->bf16 conversion: 4 weight matrices + x_qk + x_v, one launch
__global__ __launch_bounds__(256) void convAll(const float* __restrict__ w0,
    const float* __restrict__ w1, const float* __restrict__ w2,
    const float* __restrict__ w3, unsigned* __restrict__ o0,
    unsigned* __restrict__ o1, unsigned* __restrict__ o2,
    unsigned* __restrict__ o3, int wcount,
    const float* __restrict__ x0, const float* __restrict__ x1,
    unsigned* __restrict__ xo0, unsigned* __restrict__ xo1, int xcount) {
  const int nvw = wcount >> 2;
  const float* src[4] = {w0, w1, w2, w3};
  unsigned* dst[4] = {o0, o1, o2, o3};
  for (int idx = blockIdx.x * 256 + threadIdx.x; idx < 4 * nvw;
       idx += gridDim.x * 256) {
    int m = idx / nvw, r = idx - m * nvw;
    float4 v = ((const float4*)src[m])[r];
    dst[m][2 * r]     = pack2_bf16(v.x, v.y);
    dst[m][2 * r + 1] = pack2_bf16(v.z, v.w);
  }
  const int nvx = xcount >> 2;
  for (int idx = blockIdx.x * 256 + threadIdx.x; idx < 2 * nvx;
       idx += gridDim.x * 256) {
    int m = idx / nvx, r = idx - m * nvx;
    float4 v = m ? ((const float4*)x1)[r] : ((const float4*)x0)[r];
    unsigned* d = m ? xo1 : xo0;
    d[2 * r]     = pack2_bf16(v.x, v.y);
    d[2 * r + 1] = pack2_bf16(v.z, v.w);
  }
}

struct GSeg {
  const unsigned short* A;   // bf16 activations [*,768]
  const unsigned short* W;   // bf16 weights [col][k]
  const float* bias;
  const int* row_map;        // optional row gather
  float* C;                  // f32 out
  int base;                  // first flat block id of this segment
};

typedef unsigned short LdsTile[2][256][32];  // [k-panel][row][32 elems=64B]

// ---------------- 256x256 main GEMM (2-phase verified skeleton, scaled) ----
// BK=64 split into two [256][32] k-panels so rows stay 64B -> the verified
// chunk swizzle (zero bank conflicts, R3) applies. Ring-2, vmcnt(8) steady.
__global__ __launch_bounds__(512, 2) void gemm256(GSeg g0, GSeg g1, GSeg g2) {
  __shared__ __attribute__((aligned(16))) LdsTile As[2];
  __shared__ __attribute__((aligned(16))) LdsTile Bs[2];
  const int t = threadIdx.x;
  const int id = blockIdx.x;
  const GSeg& d = (id >= g2.base) ? g2 : ((id >= g1.base) ? g1 : g0);
  const int lid = id - d.base;
  const int bn = (lid % 3) * 256;
  const int bm = (lid / 3) * 256;
  const int lane = t & 63, wid = t >> 6;
  const int m16 = lane & 15, quad = lane >> 4;
  const int qx = quad ^ ((m16 >> 1) & 3);   // T2 reader involution (64B rows)
  const int wr = wid >> 2, wc = wid & 3;    // 2x4 wave grid

  f32x4 acc[8][4];
#pragma unroll
  for (int i = 0; i < 8; ++i)
#pragma unroll
    for (int j2 = 0; j2 < 4; ++j2) acc[i][j2] = (f32x4){0.f, 0.f, 0.f, 0.f};

  // staging: per K-tile each thread issues 8 DMA loads (4 A + 4 B).
  // wave wid covers LDS rows [wid*16, wid*16+16) of each 128-row half.
  const int srow = wid * 16 + (lane >> 2);                    // 0..127
  const int skc = ((lane & 3) ^ ((lane >> 3) & 3)) * 8;       // T2 source perm
  int arow0, arow1;
  if (d.row_map) {
    arow0 = d.row_map[bm + srow];
    arow1 = d.row_map[bm + 128 + srow];
  } else {
    arow0 = bm + srow;
    arow1 = bm + 128 + srow;
  }
  const int wrow0 = bn + srow, wrow1 = bn + 128 + srow;
  const int woff0 = (wid * 16) * 32;          // elems, rows half 0
  const int woff1 = (128 + wid * 16) * 32;    // rows half 1

#define STAGE256(t_, Ab, Bb) do {                                          \
    const int kk_ = (t_) * 64 + skc;                                       \
    load16_lds(d.A + (size_t)arow0 * DMODEL + kk_,      &Ab[0][0][0] + woff0); \
    load16_lds(d.A + (size_t)arow1 * DMODEL + kk_,      &Ab[0][0][0] + woff1); \
    load16_lds(d.A + (size_t)arow0 * DMODEL + kk_ + 32, &Ab[1][0][0] + woff0); \
    load16_lds(d.A + (size_t)arow1 * DMODEL + kk_ + 32, &Ab[1][0][0] + woff1); \
    load16_lds(d.W + (size_t)wrow0 * DMODEL + kk_,      &Bb[0][0][0] + woff0); \
    load16_lds(d.W + (size_t)wrow1 * DMODEL + kk_,      &Bb[0][0][0] + woff1); \
    load16_lds(d.W + (size_t)wrow0 * DMODEL + kk_ + 32, &Bb[1][0][0] + woff0); \
    load16_lds(d.W + (size_t)wrow1 * DMODEL + kk_ + 32, &Bb[1][0][0] + woff1); \
  } while (0)

#define COMPUTE256(Ab, Bb) do {                                            \
    _Pragma("unroll")                                                      \
    for (int ks = 0; ks < 2; ++ks) {                                       \
      const unsigned short* Ap = &Ab[ks][0][0];                            \
      const unsigned short* Bp = &Bb[ks][0][0];                            \
      short8 a_[8], b_[4];                                                 \
      _Pragma("unroll")                                                    \
      for (int mi = 0; mi < 8; ++mi)                                       \
        a_[mi] = *(const short8*)&Ap[(wr * 128 + mi * 16 + m16) * 32 + qx * 8]; \
      _Pragma("unroll")                                                    \
      for (int nj = 0; nj < 4; ++nj)                                       \
        b_[nj] = *(const short8*)&Bp[(wc * 64 + nj * 16 + m16) * 32 + qx * 8]; \
      __builtin_amdgcn_s_setprio(1);                                       \
      _Pragma("unroll")                                                    \
      for (int mi = 0; mi < 8; ++mi)                                       \
        _Pragma("unroll")                                                  \
        for (int nj = 0; nj < 4; ++nj)                                     \
          acc[mi][nj] = __builtin_amdgcn_mfma_f32_16x16x32_bf16(           \
              a_[mi], b_[nj], acc[mi][nj], 0, 0, 0);                       \
      __builtin_amdgcn_s_setprio(0);                                       \
    }                                                                      \
  } while (0)

  // prologue: tiles 0,1 into bufs 0,1 (16 loads in flight)
  STAGE256(0, As[0], Bs[0]);
  STAGE256(1, As[1], Bs[1]);

#pragma unroll 1
  for (int g = 0; g < 5; ++g) {      // steady tiles 0..9
    asm volatile("s_waitcnt vmcnt(8)" ::: "memory");
    __builtin_amdgcn_s_barrier();
    __builtin_amdgcn_sched_barrier(0);
    COMPUTE256(As[0], Bs[0]);
    __builtin_amdgcn_s_barrier();
    __builtin_amdgcn_sched_barrier(0);
    STAGE256(2 * g + 2, As[0], Bs[0]);
    asm volatile("s_waitcnt vmcnt(8)" ::: "memory");
    __builtin_amdgcn_s_barrier();
    __builtin_amdgcn_sched_barrier(0);
    COMPUTE256(As[1], Bs[1]);
    __builtin_amdgcn_s_barrier();
    __builtin_amdgcn_sched_barrier(0);
    STAGE256(2 * g + 3, As[1], Bs[1]);
  }
  // epilogue: tiles 10 (buf0), 11 (buf1); drain 8 -> 0
  asm volatile("s_waitcnt vmcnt(8)" ::: "memory");
  __builtin_amdgcn_s_barrier();
  __builtin_amdgcn_sched_barrier(0);
  COMPUTE256(As[0], Bs[0]);
  asm volatile("s_waitcnt vmcnt(0)" ::: "memory");
  __builtin_amdgcn_s_barrier();
  __builtin_amdgcn_sched_barrier(0);
  COMPUTE256(As[1], Bs[1]);

#undef STAGE256
#undef COMPUTE256

  // epilogue: C/D layout col=lane&15, row=quad*4+r (m89/m91)
  float bv[4]; int bcol[4];
#pragma unroll
  for (int nj = 0; nj < 4; ++nj) {
    bcol[nj] = bn + wc * 64 + nj * 16 + m16;
    bv[nj] = d.bias[bcol[nj]];
  }
#pragma unroll
  for (int mi = 0; mi < 8; ++mi) {
    const int rbase = bm + wr * 128 + mi * 16 + quad * 4;
#pragma unroll
    for (int r = 0; r < 4; ++r) {
      const int row = rbase + r;
#pragma unroll
      for (int nj = 0; nj < 4; ++nj)
        d.C[(size_t)row * DMODEL + bcol[nj]] = acc[mi][nj][r] + bv[nj];
    }
  }
}

// ---------------- 128x128 GEMM (kept for the small Wo matmul) -------------
__device__ __forceinline__ void stage_step(const GSeg& d, int k0, int arow0,
    int arow1, int wrow0, int wrow1, int skc, unsigned short* AsB,
    unsigned short* BsB, int woff) {
  load16_lds(d.A + (size_t)arow0 * DMODEL + k0 + skc, AsB + woff);
  load16_lds(d.A + (size_t)arow1 * DMODEL + k0 + skc, AsB + woff + 16 * 32);
  load16_lds(d.W + (size_t)wrow0 * DMODEL + k0 + skc, BsB + woff);
  load16_lds(d.W + (size_t)wrow1 * DMODEL + k0 + skc, BsB + woff + 16 * 32);
}

__device__ __forceinline__ void compute_step(const unsigned short* AsB,
    const unsigned short* BsB, int wm, int wn, int m16, int qx,
    f32x4 acc[4][4]) {
  short8 a[4], b[4];
#pragma unroll
  for (int i = 0; i < 4; ++i)
    a[i] = *(const short8*)&AsB[(wm + i * 16 + m16) * 32 + qx * 8];
#pragma unroll
  for (int j2 = 0; j2 < 4; ++j2)
    b[j2] = *(const short8*)&BsB[(wn + j2 * 16 + m16) * 32 + qx * 8];
  __builtin_amdgcn_s_setprio(1);
#pragma unroll
  for (int i = 0; i < 4; ++i)
#pragma unroll
    for (int j2 = 0; j2 < 4; ++j2)
      acc[i][j2] = __builtin_amdgcn_mfma_f32_16x16x32_bf16(a[i], b[j2], acc[i][j2], 0, 0, 0);
  __builtin_amdgcn_s_setprio(0);
}

__global__ __launch_bounds__(256) void gemm128(GSeg g0, GSeg g1, GSeg g2) {
  __shared__ __attribute__((aligned(16))) unsigned short As[3][128 * 32];
  __shared__ __attribute__((aligned(16))) unsigned short Bs[3][128 * 32];
  const int t = threadIdx.x;
  const int id = blockIdx.x;
  const GSeg& d = (id >= g2.base) ? g2 : ((id >= g1.base) ? g1 : g0);
  const int lid = id - d.base;
  const int xcd = lid & 7, j = lid >> 3;
  const int bn = (j % 6) * 128;
  const int bm = ((j / 6) * 8 + xcd) * 128;
  const int lane = t & 63, wid = t >> 6;
  const int m16 = lane & 15, quad = lane >> 4;
  const int qx = quad ^ ((m16 >> 1) & 3);
  const int wm = (wid >> 1) * 64, wn = (wid & 1) * 64;

  f32x4 acc[4][4];
#pragma unroll
  for (int i = 0; i < 4; ++i)
#pragma unroll
    for (int j2 = 0; j2 < 4; ++j2) acc[i][j2] = (f32x4){0.f, 0.f, 0.f, 0.f};

  const int srow = wid * 32 + (lane >> 2);
  const int skc = ((lane & 3) ^ ((lane >> 3) & 3)) * 8;
  int arow0, arow1;
  if (d.row_map) {
    arow0 = d.row_map[bm + srow];
    arow1 = d.row_map[bm + srow + 16];
  } else {
    arow0 = bm + srow;
    arow1 = bm + srow + 16;
  }
  const int wrow0 = bn + srow, wrow1 = bn + srow + 16;
  const int woff = (wid * 32) * 32;

  stage_step(d, 0,  arow0, arow1, wrow0, wrow1, skc, &As[0][0], &Bs[0][0], woff);
  stage_step(d, 32, arow0, arow1, wrow0, wrow1, skc, &As[1][0], &Bs[1][0], woff);
  stage_step(d, 64, arow0, arow1, wrow0, wrow1, skc, &As[2][0], &Bs[2][0], woff);

#pragma unroll 1
  for (int g = 0; g < (NSTEP - 3) / 3; ++g) {
    const int t0 = g * 3;
#pragma unroll
    for (int u = 0; u < 3; ++u) {
      const int ts = t0 + u;
      asm volatile("s_waitcnt vmcnt(8)" ::: "memory");
      __builtin_amdgcn_s_barrier();
      __builtin_amdgcn_sched_barrier(0);
      compute_step(&As[u][0], &Bs[u][0], wm, wn, m16, qx, acc);
      __builtin_amdgcn_s_barrier();
      __builtin_amdgcn_sched_barrier(0);
      stage_step(d, (ts + 3) * 32, arow0, arow1, wrow0, wrow1, skc,
                 &As[u][0], &Bs[u][0], woff);
    }
  }
  asm volatile("s_waitcnt vmcnt(8)" ::: "memory");
  __builtin_amdgcn_s_barrier();
  __builtin_amdgcn_sched_barrier(0);
  compute_step(&As[0][0], &Bs[0][0], wm, wn, m16, qx, acc);
  asm volatile("s_waitcnt vmcnt(4)" ::: "memory");
  __builtin_amdgcn_s_barrier();
  __builtin_amdgcn_sched_barrier(0);
  compute_step(&As[1][0], &Bs[1][0], wm, wn, m16, qx, acc);
  asm volatile("s_waitcnt vmcnt(0)" ::: "memory");
  __builtin_amdgcn_s_barrier();
  __builtin_amdgcn_sched_barrier(0);
  compute_step(&As[2][0], &Bs[2][0], wm, wn, m16, qx, acc);

  float bv[4]; int bcol[4];
#pragma unroll
  for (int j2 = 0; j2 < 4; ++j2) {
    bcol[j2] = bn + wn + j2 * 16 + m16;
    bv[j2] = d.bias[bcol[j2]];
  }
#pragma unroll
  for (int i = 0; i < 4; ++i) {
    const int rbase = bm + wm + i * 16 + quad * 4;
#pragma unroll
    for (int r = 0; r < 4; ++r) {
      const int row = rbase + r;
#pragma unroll
      for (int j2 = 0; j2 < 4; ++j2)
        d.C[(size_t)row * DMODEL + bcol[j2]] = acc[i][j2][r] + bv[j2];
    }
  }
}

// one block: prefix-scan query_mask -> left/right/nvalid per feature,
// plus compact list of fully-masked features (nvalid==0).
__global__ __launch_bounds__(1024) void build_segments(const int* __restrict__ qm,
    const int* __restrict__ ids, const int* __restrict__ padp,
    int n, int f, int* __restrict__ left, int* __restrict__ right,
    int* __restrict__ nvalid, int* __restrict__ fullrank,
    int* __restrict__ fullist, int* __restrict__ nfull) {
  __shared__ int cnt[1024];
  __shared__ int fullcnt;
  const int t = threadIdx.x;
  if (t == 0) fullcnt = 0;
  const int per = (n + 1023) >> 10;
  const int base = t * per;
  int c = 0;
  for (int i = 0; i < per; ++i) {
    int p = base + i;
    if (p < n && qm[p] != 0) ++c;
  }
  cnt[t] = c;
  __syncthreads();
  for (int off = 1; off < 1024; off <<= 1) {
    int v = (t >= off) ? cnt[t - off] : 0;
    __syncthreads();
    cnt[t] += v;
    __syncthreads();
  }
  int r = cnt[t] - c;  // exclusive prefix
  for (int i = 0; i < per; ++i) {
    int p = base + i;
    if (p < n && qm[p] != 0) {
      if (r < f) left[r] = p;
      ++r;
    }
  }
  __syncthreads();
  const int pad = *padp;
  for (int i = t; i < f; i += 1024) {
    int L0 = left[i];
    int R0 = (i + 1 < f) ? left[i + 1] : n;
    right[i] = R0;
    int cv = 0;
    for (int p = L0; p < R0; ++p) cv += (ids[p] != pad) ? 1 : 0;
    nvalid[i] = cv;
    if (cv == 0) {
      int rk = atomicAdd(&fullcnt, 1);
      if (rk < MAXFULL) { fullist[rk] = i; fullrank[i] = rk; }
      else fullrank[i] = -1;
    } else {
      fullrank[i] = -1;
    }
  }
  __syncthreads();
  if (t == 0) *nfull = (fullcnt < MAXFULL) ? fullcnt : MAXFULL;
}

__device__ __forceinline__ float allreduce64(float x) {
#pragma unroll
  for (int m = 1; m < 64; m <<= 1) x += __shfl_xor(x, m, 64);
  return x;
}

// normal features: CHUNK=8 fast path (parallel loads, one softmax), serial
// fallback otherwise.
__global__ __launch_bounds__(64) void attn_seg(const float* __restrict__ q,
    const float* __restrict__ k, const float* __restrict__ v,
    const int* __restrict__ left, const int* __restrict__ right,
    const int* __restrict__ nvalid, const int* __restrict__ ids,
    const int* __restrict__ padp, unsigned short* __restrict__ out) {
  const int feat = blockIdx.x, h = blockIdx.y, lane = threadIdx.x;
  if (nvalid[feat] == 0) return;  // handled by attn_full_*
  const int off = h * 64 + lane;
  const int pad = *padp;
  const float qv = q[(size_t)feat * DMODEL + off];
  const int L0 = left[feat], R0 = right[feat];
  if (R0 - L0 == 8) {
    float kv[8], vv[8], s[8];
    int live[8];
#pragma unroll
    for (int p = 0; p < 8; ++p) {
      kv[p] = k[(size_t)(L0 + p) * DMODEL + off];
      vv[p] = v[(size_t)(L0 + p) * DMODEL + off];
      live[p] = (ids[L0 + p] != pad);
    }
#pragma unroll
    for (int p = 0; p < 8; ++p) s[p] = qv * kv[p];
#pragma unroll
    for (int m_ = 1; m_ < 64; m_ <<= 1)
#pragma unroll
      for (int p = 0; p < 8; ++p) s[p] += __shfl_xor(s[p], m_, 64);
    float mx = -1e30f;
#pragma unroll
    for (int p = 0; p < 8; ++p) {
      s[p] = live[p] ? s[p] * 0.125f : -1e30f;
      mx = fmaxf(mx, s[p]);
    }
    float l = 0.f, acc = 0.f;
#pragma unroll
    for (int p = 0; p < 8; ++p) {
      float w = __expf(s[p] - mx);
      l += w;
      acc += w * vv[p];
    }
    out[(size_t)feat * DMODEL + off] = bf16_1(acc / l);
    return;
  }
  float m = -1e30f, l = 0.f, acc = 0.f;
  for (int p = L0; p < R0; ++p) {
    if (ids[p] == pad) continue;
    float s = allreduce64(qv * k[(size_t)p * DMODEL + off]) * 0.125f;
    float mn = fmaxf(m, s);
    float al = __expf(m - mn);
    float w = __expf(s - mn);
    l = l * al + w;
    acc = acc * al + w * v[(size_t)p * DMODEL + off];
    m = mn;
  }
  out[(size_t)feat * DMODEL + off] = bf16_1(acc / l);
}

// fully-masked features: full softmax over ALL n keys (split-K pass 1).
__global__ __launch_bounds__(256) void attn_full_part(const float* __restrict__ q,
    const float* __restrict__ k, const float* __restrict__ v,
    const int* __restrict__ fullist, const int* __restrict__ nfullp,
    int n, int P, float* __restrict__ pm, float* __restrict__ pl,
    float* __restrict__ pacc) {
  const int nfull = *nfullp;
  if (nfull == 0) return;
  const int t = threadIdx.x, lane = t & 63, wv = t >> 6;
  const int gw = blockIdx.x * 4 + wv;     // P % 4 == 0 -> block-uniform head
  const int h = gw / P, piece = gw - h * P;
  const int pk = n / P;                    // keys per piece (multiple of 64)

  __shared__ float q_lds[8 * 64];
  __shared__ float w_lds[4][64 * 8];       // [wave][key][feat]

  for (int idx = t; idx < 8 * 64; idx += 256) {
    int fl = idx >> 6, d = idx & 63;
    q_lds[idx] = (fl < nfull) ? q[(size_t)fullist[fl] * DMODEL + h * 64 + d] : 0.f;
  }
  __syncthreads();

  float m[8], l[8], acc[8];
#pragma unroll
  for (int f_ = 0; f_ < 8; ++f_) { m[f_] = -1e30f; l[f_] = 0.f; acc[f_] = 0.f; }

  for (int c = 0; c < pk; c += 64) {
    const int pc = piece * pk + c;
    float s[8];
#pragma unroll
    for (int f_ = 0; f_ < 8; ++f_) s[f_] = 0.f;
    const float4* kp = (const float4*)(k + (size_t)(pc + lane) * DMODEL + h * 64);
#pragma unroll 1
    for (int g = 0; g < 2; ++g) {
      float4 kv0 = kp[g * 8 + 0], kv1 = kp[g * 8 + 1], kv2 = kp[g * 8 + 2],
             kv3 = kp[g * 8 + 3], kv4 = kp[g * 8 + 4], kv5 = kp[g * 8 + 5],
             kv6 = kp[g * 8 + 6], kv7 = kp[g * 8 + 7];
      const float4* qb = (const float4*)&q_lds[g * 32];
#pragma unroll
      for (int f_ = 0; f_ < 8; ++f_) {
        float4 q0 = qb[f_ * 16 + 0], q1 = qb[f_ * 16 + 1], q2 = qb[f_ * 16 + 2],
               q3 = qb[f_ * 16 + 3], q4 = qb[f_ * 16 + 4], q5 = qb[f_ * 16 + 5],
               q6 = qb[f_ * 16 + 6], q7 = qb[f_ * 16 + 7];
        float acc0 = q0.x * kv0.x + q0.y * kv0.y + q0.z * kv0.z + q0.w * kv0.w;
        acc0 += q1.x * kv1.x + q1.y * kv1.y + q1.z * kv1.z + q1.w * kv1.w;
        acc0 += q2.x * kv2.x + q2.y * kv2.y + q2.z * kv2.z + q2.w * kv2.w;
        acc0 += q3.x * kv3.x + q3.y * kv3.y + q3.z * kv3.z + q3.w * kv3.w;
        acc0 += q4.x * kv4.x + q4.y * kv4.y + q4.z * kv4.z + q4.w * kv4.w;
        acc0 += q5.x * kv5.x + q5.y * kv5.y + q5.z * kv5.z + q5.w * kv5.w;
        acc0 += q6.x * kv6.x + q6.y * kv6.y + q6.z * kv6.z + q6.w * kv6.w;
        acc0 += q7.x * kv7.x + q7.y * kv7.y + q7.z * kv7.z + q7.w * kv7.w;
        s[f_] += acc0;
      }
    }
    float mx[8];
#pragma unroll
    for (int f_ = 0; f_ < 8; ++f_) mx[f_] = s[f_] * 0.125f;
#pragma unroll
    for (int f_ = 0; f_ < 8; ++f_) s[f_] = mx[f_];
#pragma unroll
    for (int st = 1; st < 64; st <<= 1)
#pragma unroll
      for (int f_ = 0; f_ < 8; ++f_) mx[f_] = fmaxf(mx[f_], __shfl_xor(mx[f_], st, 64));
    float alpha[8], w[8], sum[8];
#pragma unroll
    for (int f_ = 0; f_ < 8; ++f_) {
      float mn = fmaxf(m[f_], mx[f_]);
      alpha[f_] = __expf(m[f_] - mn);
      w[f_] = __expf(s[f_] - mn);
      m[f_] = mn;
      sum[f_] = w[f_];
    }
#pragma unroll
    for (int st = 1; st < 64; st <<= 1)
#pragma unroll
      for (int f_ = 0; f_ < 8; ++f_) sum[f_] += __shfl_xor(sum[f_], st, 64);
#pragma unroll
    for (int f_ = 0; f_ < 8; ++f_) l[f_] = l[f_] * alpha[f_] + sum[f_];
    *(float4*)&w_lds[wv][lane * 8]     = make_float4(w[0], w[1], w[2], w[3]);
    *(float4*)&w_lds[wv][lane * 8 + 4] = make_float4(w[4], w[5], w[6], w[7]);
#pragma unroll
    for (int f_ = 0; f_ < 8; ++f_) acc[f_] *= alpha[f_];
    const float* vb = v + (size_t)pc * DMODEL + h * 64 + lane;
#pragma unroll 4
    for (int kk = 0; kk < 64; ++kk) {
      float vd = vb[(size_t)kk * DMODEL];
      float4 wa = *(const float4*)&w_lds[wv][kk * 8];
      float4 wb = *(const float4*)&w_lds[wv][kk * 8 + 4];
      acc[0] += wa.x * vd; acc[1] += wa.y * vd; acc[2] += wa.z * vd; acc[3] += wa.w * vd;
      acc[4] += wb.x * vd; acc[5] += wb.y * vd; acc[6] += wb.z * vd; acc[7] += wb.w * vd;
    }
  }

  for (int f_ = 0; f_ < nfull; ++f_) {
    size_t idx = ((size_t)f_ * NHEADS + h) * P + piece;
    if (lane == 0) { pm[idx] = m[f_]; pl[idx] = l[f_]; }
    pacc[idx * 64 + lane] = acc[f_];
  }
}

// Split-K pass 2: merge the P partials per (full-feature, head). Writes bf16.
__global__ __launch_bounds__(256) void attn_full_comb(
    const int* __restrict__ fullist, const int* __restrict__ nfullp,
    int P, const float* __restrict__ pm, const float* __restrict__ pl,
    const float* __restrict__ pacc, unsigned short* __restrict__ out) {
  const int fl = blockIdx.x, h = blockIdx.y;
  if (fl >= *nfullp) return;
  const int feat = fullist[fl];
  const int t = threadIdx.x, lane = t & 63, wv = t >> 6;
  const size_t base = ((size_t)fl * NHEADS + h) * P;

  __shared__ float s_pm[128];    // P <= 128
  __shared__ float s_sc[128];
  __shared__ float s_red[4];
  __shared__ float s_part[4][64];

  for (int sp = t; sp < P; sp += 256) s_pm[sp] = pm[base + sp];
  __syncthreads();
  float mloc = -1e30f;
  for (int sp = t; sp < P; sp += 256) mloc = fmaxf(mloc, s_pm[sp]);
#pragma unroll
  for (int st = 1; st < 64; st <<= 1) mloc = fmaxf(mloc, __shfl_xor(mloc, st, 64));
  if (lane == 0) s_red[wv] = mloc;
  __syncthreads();
  const float M = fmaxf(fmaxf(s_red[0], s_red[1]), fmaxf(s_red[2], s_red[3]));
  __syncthreads();
  float lloc = 0.f;
  for (int sp = t; sp < P; sp += 256) {
    float sc = __expf(s_pm[sp] - M);
    s_sc[sp] = sc;
    lloc += pl[base + sp] * sc;
  }
#pragma unroll
  for (int st = 1; st < 64; st <<= 1) lloc += __shfl_xor(lloc, st, 64);
  if (lane == 0) s_red[wv] = lloc;
  __syncthreads();
  const float Lt = s_red[0] + s_red[1] + s_red[2] + s_red[3];
  float At = 0.f;
  for (int sp = wv; sp < P; sp += 4)
    At += pacc[(base + sp) * 64 + lane] * s_sc[sp];
  s_part[wv][lane] = At;
  __syncthreads();
  if (wv == 0) {
    float tot = s_part[0][lane] + s_part[1][lane] + s_part[2][lane] + s_part[3][lane];
    out[(size_t)feat * DMODEL + h * 64 + lane] = bf16_1(tot / Lt);
  }
}

extern "C" void kernel_launch(void* const* d_in, const int* in_sizes, int n_in,
                              void* d_out, int out_size, void* d_ws, size_t ws_size,
                              hipStream_t stream) {
  const float* x_qk = (const float*)d_in[0];
  const float* x_v  = (const float*)d_in[1];
  const int* qm     = (const int*)d_in[2];
  const int* ids    = (const int*)d_in[3];
  const int* padp   = (const int*)d_in[4];
  const float* Wq = (const float*)d_in[5];
  const float* bq = (const float*)d_in[6];
  const float* Wk = (const float*)d_in[7];
  const float* bk = (const float*)d_in[8];
  const float* Wv = (const float*)d_in[9];
  const float* bv = (const float*)d_in[10];
  const float* Wo = (const float*)d_in[11];
  const float* bo = (const float*)d_in[12];

  const int n = in_sizes[0] / DMODEL;   // 8192
  const int f = out_size / DMODEL;      // 1024

  // ws: kf,vf,qf f32 | af bf16 | Wbf x4 | xqb,xvb bf16 | ints | split partials
  float* kf = (float*)d_ws;
  float* vf = kf + (size_t)n * DMODEL;
  float* qf = vf + (size_t)n * DMODEL;
  unsigned short* af = (unsigned short*)(qf + (size_t)f * DMODEL);
  unsigned short* wqb = af + (size_t)f * DMODEL;
  unsigned short* wkb = wqb + DMODEL * DMODEL;
  unsigned short* wvb = wkb + DMODEL * DMODEL;
  unsigned short* wob = wvb + DMODEL * DMODEL;
  unsigned short* xqb = wob + DMODEL * DMODEL;
  unsigned short* xvb = xqb + (size_t)n * DMODEL;
  int* left     = (int*)(xvb + (size_t)n * DMODEL);
  int* right    = left + f;
  int* nvalid   = right + f;
  int* fullrank = nvalid + f;
  int* fullist  = fullrank + f;
  int* nfull    = fullist + MAXFULL;
  size_t off_bytes = ((size_t)((char*)(nfull + 1) - (char*)d_ws) + 255) & ~(size_t)255;
  int P = 128;
  while (P > 16) {
    size_t need = (size_t)MAXFULL * NHEADS * P * 66 * sizeof(float);
    if (off_bytes + need <= ws_size && (n / P) % 64 == 0 && n % P == 0) break;
    P >>= 1;
  }
  float* pm = (float*)((char*)d_ws + off_bytes);
  float* pl = pm + (size_t)MAXFULL * NHEADS * P;
  float* pacc = pl + (size_t)MAXFULL * NHEADS * P;

  build_segments<<<1, 1024, 0, stream>>>(qm, ids, padp, n, f, left, right,
                                         nvalid, fullrank, fullist, nfull);
  convAll<<<2048, 256, 0, stream>>>(Wq, Wk, Wv, Wo, (unsigned*)wqb,
                                    (unsigned*)wkb, (unsigned*)wvb,
                                    (unsigned*)wob, DMODEL * DMODEL,
                                    x_qk, x_v, (unsigned*)xqb, (unsigned*)xvb,
                                    n * DMODEL);

  // main QKV GEMM at 256x256: K (96) | V (96) | Q-gather (12) = 204 blocks
  const int TKV256 = 3 * (n / 256);   // 96
  const int TF256  = 3 * (f / 256);   // 12
  GSeg g0 = { xqb, wkb, bk, nullptr, kf, 0 };
  GSeg g1 = { xvb, wvb, bv, nullptr, vf, TKV256 };
  GSeg g2 = { xqb, wqb, bq, left,    qf, 2 * TKV256 };
  gemm256<<<2 * TKV256 + TF256, 512, 0, stream>>>(g0, g1, g2);

  attn_seg<<<dim3(f, NHEADS), 64, 0, stream>>>(qf, kf, vf, left, right, nvalid,
                                               ids, padp, af);
  attn_full_part<<<NHEADS * P / 4, 256, 0, stream>>>(qf, kf, vf, fullist, nfull,
                                                     n, P, pm, pl, pacc);
  attn_full_comb<<<dim3(MAXFULL, NHEADS), 256, 0, stream>>>(fullist, nfull, P,
                                                            pm, pl, pacc, af);

  const int TF  = 6 * (f / 128);   // 48 blocks
  GSeg gout = { af, wob, bo, nullptr, (float*)d_out, 0 };
  GSeg gnull = { af, wob, bo, nullptr, (float*)d_out, 1 << 30 };
  gemm128<<<TF, 256, 0, stream>>>(gout, gnull, gnull);
}